// Round 10
// baseline (182.927 us; speedup 1.0000x reference)
//
#include <hip/hip_runtime.h>
#include <hip/hip_bf16.h>
#include <stdint.h>

// Problem constants
#define Bn 4
#define Ln 1024
#define Dn 1024
#define Hn 16
#define DHn 64
#define Mn (Bn*Ln)   // 4096 tokens

typedef __attribute__((ext_vector_type(8))) short short8v;   // 8 x bf16 (4 VGPRs)
typedef __attribute__((ext_vector_type(4))) float floatx4;   // MFMA accumulator

__device__ __forceinline__ unsigned short f2b(float f){
  union { float f; unsigned u; } v; v.f = f;
  unsigned r = (v.u + 0x7FFFu + ((v.u >> 16) & 1u)) >> 16;  // RNE
  return (unsigned short)r;
}
__device__ __forceinline__ unsigned short f2b_fast(float f){
  __hip_bfloat16 h = __float2bfloat16(f);   // compiler-native cvt (RNE)
  return *reinterpret_cast<unsigned short*>(&h);
}

// global -> LDS direct copy, 16B per lane.
typedef const unsigned __attribute__((address_space(1)))* gas1_t;
typedef unsigned __attribute__((address_space(3)))* las3_t;
__device__ __forceinline__ void gload16(const void* g, void* l){
  __builtin_amdgcn_global_load_lds((gas1_t)(uintptr_t)g, (las3_t)(uintptr_t)l, 16, 0, 0);
}

// ---------------------------------------------------------------------------
// fp32 -> bf16 streaming convert, all three inputs in one launch
// ---------------------------------------------------------------------------
__global__ __launch_bounds__(256) void tobf16x3_k(const float* __restrict__ x0,
    const float* __restrict__ x1, const float* __restrict__ x2,
    unsigned short* __restrict__ o0, unsigned short* __restrict__ o1,
    unsigned short* __restrict__ o2)
{
  const int i = blockIdx.x * 256 + threadIdx.x;      // [0, 3*2^20)
  const int sel = i >> 20, idx = i & 0xFFFFF;
  const float* x = sel == 0 ? x0 : (sel == 1 ? x1 : x2);
  unsigned short* o = sel == 0 ? o0 : (sel == 1 ? o1 : o2);
  float4 v = reinterpret_cast<const float4*>(x)[idx];
  union { unsigned short u[4]; uint2 q; } p;
  p.u[0] = f2b(v.x); p.u[1] = f2b(v.y); p.u[2] = f2b(v.z); p.u[3] = f2b(v.w);
  reinterpret_cast<uint2*>(o)[idx] = p.q;
}

// ---------------------------------------------------------------------------
// Weight transpose + fp32->bf16 convert, all 4 weights in one launch
// ---------------------------------------------------------------------------
__global__ __launch_bounds__(256) void wconv4_k(const float* __restrict__ W0,
    const float* __restrict__ W1, const float* __restrict__ W2,
    const float* __restrict__ W3, unsigned short* __restrict__ Wt0,
    unsigned short* __restrict__ Wt1, unsigned short* __restrict__ Wt2,
    unsigned short* __restrict__ Wt3)
{
  const float* W; unsigned short* Wt;
  switch (blockIdx.z){
    case 0: W = W0; Wt = Wt0; break;
    case 1: W = W1; Wt = Wt1; break;
    case 2: W = W2; Wt = Wt2; break;
    default: W = W3; Wt = Wt3; break;
  }
  __shared__ float tile[64][65];
  const int nb = blockIdx.x * 64, kb = blockIdx.y * 64;
  const int tx = threadIdx.x & 63, ty = threadIdx.x >> 6;  // ty 0..3
  #pragma unroll
  for (int r = 0; r < 64; r += 4)
    tile[r + ty][tx] = W[(size_t)(kb + r + ty) * 1024 + nb + tx];
  __syncthreads();
  #pragma unroll
  for (int r = 0; r < 64; r += 4)
    Wt[(size_t)(nb + r + ty) * 1024 + kb + tx] = f2b(tile[tx][r + ty]);
}

// ---------------------------------------------------------------------------
// GEMM core v5 -- BARRIER-FREE wave-private pipeline.
// Block = 128x128 C; wave w (2x2: wr=w>>1, wc=w&1) owns a 64x64 C-tile and
// stages its own A-strip (64 rows) and B-strip (64 cols of Bt) privately.
// Per wave: 16KB LDS (2 bufs x {4KB A + 4KB B}), BK=32 halves, 32 iters:
//   { issue 8 gloads for h+1 into buf^1 -> s_waitcnt vmcnt(8) (h's loads
//     done, h+1's in flight; PER-WAVE, no cross-wave coupling) ->
//     8 ds_read_b128 + 16 MFMA }
// NO __syncthreads in the loop: waves drift out of phase and co-schedule
// (MFMA pipe of one covers load latency of another). A/B read 2x per block
// from L2 (the price of privacy; L2-resident).
//  MODE 0: out bf16 [B,H,L,DH]
//  MODE 2: out bf16 [B,H,DH,L] via XOR-swizzled LDS transpose (16B stores)
//  MODE 3: out fp32 [M,D] = acc + bias + resid (pre-layernorm x)
// ---------------------------------------------------------------------------
template<int MODE>
__device__ __forceinline__ void gemm_core(const unsigned short* __restrict__ Ab,
    const unsigned short* __restrict__ Btp, const float* __restrict__ bias,
    void* __restrict__ outp, const float* __restrict__ resid, float scale,
    unsigned short* lds, int nt, int mt)
{
  const int tid = threadIdx.x;
  const int lane = tid & 63, wave = tid >> 6;
  const int wr = wave >> 1, wc = wave & 1;
  const int lg = lane >> 4, lr = lane & 15;
  const int m0 = mt * 128, n0 = nt * 128;

  unsigned short* wlds = lds + wave * 8192;       // 16KB private

  // per-lane global srcs for the wave's 4 A-chunks + 4 B-chunks (per half)
  const unsigned short* gA[4];
  const unsigned short* gB[4];
  #pragma unroll
  for (int c = 0; c < 4; c++){
    gA[c] = Ab  + (size_t)(m0 + wr * 64 + c * 16 + lr) * 1024 + lg * 8;
    gB[c] = Btp + (size_t)(n0 + wc * 64 + c * 16 + lr) * 1024 + lg * 8;
  }

  floatx4 acc[4][4] = {};

  // prologue: half 0 -> buf 0
  #pragma unroll
  for (int c = 0; c < 4; c++){
    gload16(gA[c], &wlds[c * 512]);
    gload16(gB[c], &wlds[2048 + c * 512]);
  }

  for (int h = 0; h < 32; h++){
    const int cur = (h & 1) * 4096;
    if (h < 31){
      const int nxt = 4096 - cur;
      const int off = (h + 1) * 32;
      #pragma unroll
      for (int c = 0; c < 4; c++){
        gload16(gA[c] + off, &wlds[nxt + c * 512]);
        gload16(gB[c] + off, &wlds[nxt + 2048 + c * 512]);
      }
      asm volatile("s_waitcnt vmcnt(8)" ::: "memory");  // h landed; h+1 in flight
    } else {
      asm volatile("s_waitcnt vmcnt(0)" ::: "memory");
    }
    __builtin_amdgcn_sched_barrier(0);
    short8v af[4], bf[4];
    #pragma unroll
    for (int m = 0; m < 4; m++)
      af[m] = *reinterpret_cast<const short8v*>(&wlds[cur + (m * 64 + lane) * 8]);
    #pragma unroll
    for (int n = 0; n < 4; n++)
      bf[n] = *reinterpret_cast<const short8v*>(&wlds[cur + 2048 + (n * 64 + lane) * 8]);
    #pragma unroll
    for (int m = 0; m < 4; m++)
      #pragma unroll
      for (int n = 0; n < 4; n++)
        acc[m][n] = __builtin_amdgcn_mfma_f32_16x16x32_bf16(af[m], bf[n], acc[m][n], 0, 0, 0);
  }

  if constexpr (MODE == 2){
    // transpose epilogue: stage C^T (bf16) in shared LDS with XOR swizzle,
    // then write V^T rows as contiguous 16B chunks.
    __syncthreads();                   // all waves out of their private K-loops
    #pragma unroll
    for (int n = 0; n < 4; n++){
      const int gn_l = wc * 64 + n * 16 + lr;        // d-dim local row
      const float bb = bias[n0 + gn_l];
      const int X = (gn_l & 7) << 3;
      #pragma unroll
      for (int m = 0; m < 4; m++){
        const int gm_l = wr * 64 + m * 16 + lg * 4;  // token local col
        union { unsigned short u[4]; uint2 q; } pk;
        #pragma unroll
        for (int r = 0; r < 4; r++) pk.u[r] = f2b((acc[m][n][r] + bb) * scale);
        *reinterpret_cast<uint2*>(&lds[gn_l * 128 + (gm_l ^ X)]) = pk.q;
      }
    }
    __syncthreads();
    const int b = m0 >> 10, l0 = m0 & 1023;
    const int row = tid >> 1, colb = (tid & 1) * 64;  // row: d-dim, col: token
    const int h2 = (n0 + row) >> 6, d = (n0 + row) & 63;
    unsigned short* obase = (unsigned short*)outp +
        (((size_t)(b * Hn + h2)) * DHn + d) * Ln + l0 + colb;
    const int XR = (row & 7) << 3;
    #pragma unroll
    for (int g = 0; g < 8; g++){
      short8v v = *reinterpret_cast<const short8v*>(&lds[row * 128 + ((colb + g * 8) ^ XR)]);
      *reinterpret_cast<short8v*>(obase + g * 8) = v;
    }
  } else {
    #pragma unroll
    for (int n = 0; n < 4; n++){
      const int gn = n0 + wc * 64 + n * 16 + lr;
      const float bb = bias[gn];
      #pragma unroll
      for (int m = 0; m < 4; m++){
        const int gm0 = m0 + wr * 64 + m * 16 + lg * 4;
        #pragma unroll
        for (int r = 0; r < 4; r++){
          const int gm = gm0 + r;
          float v = (acc[m][n][r] + bb) * scale;
          if constexpr (MODE == 0){
            unsigned short* o = (unsigned short*)outp;
            int b = gm >> 10, l = gm & 1023, h2 = gn >> 6, d = gn & 63;
            o[(((size_t)(b * Hn + h2)) * Ln + l) * DHn + d] = f2b(v);
          } else {
            float* o = (float*)outp;
            o[(size_t)gm * Dn + gn] = v + resid[(size_t)gm * Dn + gn];
          }
        }
      }
    }
  }
}

// Fused Q/K/V projections: 768 blocks. XCD-panel affinity, z interleaved.
__global__ __launch_bounds__(256) void gemmqkv_k(
    const unsigned short* __restrict__ A0, const unsigned short* __restrict__ A1,
    const unsigned short* __restrict__ A2, const unsigned short* __restrict__ W0,
    const unsigned short* __restrict__ W1, const unsigned short* __restrict__ W2,
    const float* __restrict__ b0, const float* __restrict__ b1,
    const float* __restrict__ b2, unsigned short* __restrict__ o0,
    unsigned short* __restrict__ o1, unsigned short* __restrict__ o2, float qscl)
{
  __shared__ __align__(16) unsigned short lds[32768];   // 64KB: 4 waves x 16KB
  const int bid = blockIdx.x;
  const int xcd = bid & 7, k = bid >> 3;       // k: 0..95
  const int panel = (k >> 3) * 8 + xcd;        // 0..95; 12 panels/XCD, 4 per z
  const int nt = k & 7;                        // 0..7
  const int mt = panel & 31, z = panel >> 5;
  if (z == 0)
    gemm_core<0>(A0, W0, b0, o0, nullptr, qscl, lds, nt, mt);
  else if (z == 1)
    gemm_core<0>(A1, W1, b1, o1, nullptr, 1.f, lds, nt, mt);
  else
    gemm_core<2>(A2, W2, b2, o2, nullptr, 1.f, lds, nt, mt);
}

// O projection + residual: 256 blocks (32 mt x 8 nt), XCD affinity.
__global__ __launch_bounds__(256) void gemmo_k(const unsigned short* __restrict__ Ab,
    const unsigned short* __restrict__ W, const float* __restrict__ bias,
    float* __restrict__ out, const float* __restrict__ resid)
{
  __shared__ __align__(16) unsigned short lds[32768];
  const int bid = blockIdx.x;
  const int xcd = bid & 7, k = bid >> 3;       // k: 0..31
  const int mt = (k >> 3) * 8 + xcd;
  const int nt = k & 7;
  gemm_core<3>(Ab, W, bias, out, resid, 1.f, lds, nt, mt);
}

// ---------------------------------------------------------------------------
// Flash attention v6 (unchanged): grid (B*H, L/128), 4 waves x 32 q-rows,
// KVBLK=64, no-max exp2 softmax, deferred denominator, dbuf K/V via
// global_load_lds, mask prefetch.
// ---------------------------------------------------------------------------
__global__ __launch_bounds__(256) void attn_k(const unsigned short* __restrict__ qb,
    const unsigned short* __restrict__ kbf, const unsigned short* __restrict__ vtb,
    const int* __restrict__ kmask, unsigned short* __restrict__ ctx)
{
  const int bh = blockIdx.x;        // 0..63
  const int qt = blockIdx.y;        // 0..7
  const int b = bh >> 4, h = bh & 15;
  const int tid = threadIdx.x;
  const int w = tid >> 6, lane = tid & 63;
  const int lg = lane >> 4, lr = lane & 15;

  const unsigned short* qp = qb  + (size_t)bh * Ln * DHn;
  const unsigned short* kp = kbf + (size_t)bh * Ln * DHn;
  const unsigned short* vp = vtb + (size_t)bh * DHn * Ln;
  const int q0 = qt * 128 + w * 32;

  __shared__ __align__(16) unsigned short ldsK[2][4096];   // 2 x 8KB
  __shared__ __align__(16) unsigned short ldsV[2][4096];
  __shared__ __align__(16) unsigned short plds[4][32][72]; // per-wave P (32 q-rows)

  const unsigned short* gK[2];
  const unsigned short* gV[2];
  #pragma unroll
  for (int i = 0; i < 2; i++){
    int bc = w * 2 + i;             // 0..7
    int ks = bc >> 2, j = bc & 3;
    int row = j * 16 + lr, col = ks * 32 + lg * 8;
    gK[i] = kp + (size_t)row * DHn + col;   // + t*4096 per tile
    gV[i] = vp + (size_t)row * Ln  + col;   // + t*64 per tile
  }

  short8v aq[2][2];                  // [qfrag][ks]
  #pragma unroll
  for (int f = 0; f < 2; f++)
    #pragma unroll
    for (int ks = 0; ks < 2; ks++)
      aq[f][ks] = *reinterpret_cast<const short8v*>(
          qp + (size_t)(q0 + f * 16 + lr) * DHn + ks * 32 + lg * 8);

  floatx4 accO[2][4] = {};
  float lsacc[2][4] = {{0.f,0.f,0.f,0.f},{0.f,0.f,0.f,0.f}};

  const int* mrow = kmask + b * Ln;
  int mkA[4], mkB[4];

  #pragma unroll
  for (int i = 0; i < 2; i++){
    gload16(gK[i], &ldsK[0][(w * 2 + i) * 512]);
    gload16(gV[i], &ldsV[0][(w * 2 + i) * 512]);
  }
  #pragma unroll
  for (int j = 0; j < 4; j++) mkA[j] = mrow[j * 16 + lr];

  for (int t = 0; t < 16; t++){
    const int cur = t & 1;
    asm volatile("s_waitcnt vmcnt(0)" ::: "memory");
    __syncthreads();
    if (t < 15){
      #pragma unroll
      for (int i = 0; i < 2; i++){
        gload16(gK[i] + (size_t)(t + 1) * 4096, &ldsK[cur ^ 1][(w * 2 + i) * 512]);
        gload16(gV[i] + (size_t)(t + 1) * 64,   &ldsV[cur ^ 1][(w * 2 + i) * 512]);
      }
      #pragma unroll
      for (int j = 0; j < 4; j++) mkB[j] = mrow[(t + 1) * 64 + j * 16 + lr];
    }

    floatx4 s[2][4] = {};
    #pragma unroll
    for (int ks = 0; ks < 2; ks++)
      #pragma unroll
      for (int j = 0; j < 4; j++){
        short8v bk = *reinterpret_cast<const short8v*>(&ldsK[cur][((ks * 4 + j) * 64 + lane) * 8]);
        s[0][j] = __builtin_amdgcn_mfma_f32_16x16x32_bf16(aq[0][ks], bk, s[0][j], 0, 0, 0);
        s[1][j] = __builtin_amdgcn_mfma_f32_16x16x32_bf16(aq[1][ks], bk, s[1][j], 0, 0, 0);
      }
    if (__all(mkA[0] > 0 && mkA[1] > 0 && mkA[2] > 0 && mkA[3] > 0)){
      #pragma unroll
      for (int f = 0; f < 2; f++)
        #pragma unroll
        for (int j = 0; j < 4; j++)
          #pragma unroll
          for (int r = 0; r < 4; r++){
            float p = __builtin_amdgcn_exp2f(s[f][j][r]);
            lsacc[f][r] += p;
            plds[w][f * 16 + lg * 4 + r][j * 16 + lr] = f2b_fast(p);
          }
    } else {
      #pragma unroll
      for (int j = 0; j < 4; j++){
        const float madd = mkA[j] > 0 ? 0.f : -1e9f;
        #pragma unroll
        for (int f = 0; f < 2; f++)
          #pragma unroll
          for (int r = 0; r < 4; r++){
            float p = __builtin_amdgcn_exp2f(s[f][j][r] + madd);
            lsacc[f][r] += p;
            plds[w][f * 16 + lg * 4 + r][j * 16 + lr] = f2b_fast(p);
          }
      }
    }
    #pragma unroll
    for (int ks = 0; ks < 2; ks++){
      short8v pa0 = *reinterpret_cast<const short8v*>(&plds[w][lr][ks * 32 + lg * 8]);
      short8v pa1 = *reinterpret_cast<const short8v*>(&plds[w][16 + lr][ks * 32 + lg * 8]);
      #pragma unroll
      for (int n = 0; n < 4; n++){
        short8v bv = *reinterpret_cast<const short8v*>(&ldsV[cur][((ks * 4 + n) * 64 + lane) * 8]);
        accO[0][n] = __builtin_amdgcn_mfma_f32_16x16x32_bf16(pa0, bv, accO[0][n], 0, 0, 0);
        accO[1][n] = __builtin_amdgcn_mfma_f32_16x16x32_bf16(pa1, bv, accO[1][n], 0, 0, 0);
      }
    }
    #pragma unroll
    for (int j = 0; j < 4; j++) mkA[j] = mkB[j];
  }

  #pragma unroll
  for (int f = 0; f < 2; f++)
    #pragma unroll
    for (int r = 0; r < 4; r++){
      lsacc[f][r] += __shfl_xor(lsacc[f][r], 1, 64);
      lsacc[f][r] += __shfl_xor(lsacc[f][r], 2, 64);
      lsacc[f][r] += __shfl_xor(lsacc[f][r], 4, 64);
      lsacc[f][r] += __shfl_xor(lsacc[f][r], 8, 64);
      lsacc[f][r] = 1.f / fmaxf(lsacc[f][r], 1e-20f);
    }
  #pragma unroll
  for (int f = 0; f < 2; f++)
    #pragma unroll
    for (int n = 0; n < 4; n++)
      #pragma unroll
      for (int r = 0; r < 4; r++){
        float o = accO[f][n][r] * lsacc[f][r];
        int q = q0 + f * 16 + lg * 4 + r;
        ctx[((size_t)(b * Ln + q)) * Dn + h * DHn + n * 16 + lr] = f2b_fast(o);
      }
}

// ---------------------------------------------------------------------------
// LayerNorm: one block per row of x[4096][1024] fp32 -> out fp32
// ---------------------------------------------------------------------------
__global__ __launch_bounds__(256) void ln_k(const float* __restrict__ x,
    const float* __restrict__ g, const float* __restrict__ bt, float* __restrict__ out)
{
  const int row = blockIdx.x;
  const int tid = threadIdx.x;
  float4 v = *reinterpret_cast<const float4*>(x + (size_t)row * 1024 + tid * 4);
  float s  = v.x + v.y + v.z + v.w;
  float sq = v.x * v.x + v.y * v.y + v.z * v.z + v.w * v.w;
  #pragma unroll
  for (int off = 32; off >= 1; off >>= 1){
    s  += __shfl_xor(s, off, 64);
    sq += __shfl_xor(sq, off, 64);
  }
  __shared__ float psm[4], pqm[4];
  const int w = tid >> 6;
  if ((tid & 63) == 0){ psm[w] = s; pqm[w] = sq; }
  __syncthreads();
  s  = psm[0] + psm[1] + psm[2] + psm[3];
  sq = pqm[0] + pqm[1] + pqm[2] + pqm[3];
  const float mean = s * (1.f / 1024.f);
  const float var  = sq * (1.f / 1024.f) - mean * mean;
  const float inv  = rsqrtf(var + 1e-5f);
  float4 gg = *reinterpret_cast<const float4*>(g  + tid * 4);
  float4 bb = *reinterpret_cast<const float4*>(bt + tid * 4);
  float4 o;
  o.x = (v.x - mean) * inv * gg.x + bb.x;
  o.y = (v.y - mean) * inv * gg.y + bb.y;
  o.z = (v.z - mean) * inv * gg.z + bb.z;
  o.w = (v.w - mean) * inv * gg.w + bb.w;
  *reinterpret_cast<float4*>(out + (size_t)row * 1024 + tid * 4) = o;
}

// ---------------------------------------------------------------------------
extern "C" void kernel_launch(void* const* d_in, const int* in_sizes, int n_in,
                              void* d_out, int out_size, void* d_ws, size_t ws_size,
                              hipStream_t stream)
{
  const float* Qin = (const float*)d_in[0];
  const float* Kin = (const float*)d_in[1];
  const float* Vin = (const float*)d_in[2];
  const int*   Kms = (const int*)d_in[3];
  const float* WQ  = (const float*)d_in[4];
  const float* bQ  = (const float*)d_in[5];
  const float* WK  = (const float*)d_in[6];
  const float* bK  = (const float*)d_in[7];
  const float* WV  = (const float*)d_in[8];
  const float* bV  = (const float*)d_in[9];
  const float* WO  = (const float*)d_in[10];
  const float* bO  = (const float*)d_in[11];
  const float* lng = (const float*)d_in[12];
  const float* lnb = (const float*)d_in[13];

  char* ws = (char*)d_ws;
  const size_t MB = 1024u * 1024u;
  unsigned short* wqt = (unsigned short*)(ws + 0 * MB);    // 1024x1024 bf16 = 2MB
  unsigned short* wkt = (unsigned short*)(ws + 2 * MB);
  unsigned short* wvt = (unsigned short*)(ws + 4 * MB);
  unsigned short* wot = (unsigned short*)(ws + 6 * MB);
  unsigned short* qbf = (unsigned short*)(ws + 8 * MB);    // [B,H,L,DH] bf16 = 8MB
  unsigned short* kbf = (unsigned short*)(ws + 16 * MB);
  unsigned short* vtb = (unsigned short*)(ws + 24 * MB);   // [B,H,DH,L]
  unsigned short* ctx = (unsigned short*)(ws + 32 * MB);   // [B,L,D] bf16
  float*          xbf = (float*)(ws + 40 * MB);            // [M,D] fp32 = 16MB
  // bf16 copies of Q,K,V inputs -- alias regions that are dead until later:
  unsigned short* cv0 = (unsigned short*)(ws + 32 * MB);   // aliases ctx (written later by attn)
  unsigned short* cv1 = (unsigned short*)(ws + 40 * MB);   // aliases xbf[0:8MB] (written later by gemmo)
  unsigned short* cv2 = (unsigned short*)(ws + 48 * MB);   // aliases xbf[8:16MB]

  dim3 blk(256);
  wconv4_k<<<dim3(16, 16, 4), blk, 0, stream>>>(WQ, WK, WV, WO, wqt, wkt, wvt, wot);
  tobf16x3_k<<<12288, blk, 0, stream>>>(Qin, Kin, Vin, cv0, cv1, cv2);

  const float QSCL = 0.125f * 1.44269504088896f;  // fold 1/sqrt(dh) * log2(e) into q
  gemmqkv_k<<<768, blk, 0, stream>>>(cv0, cv1, cv2, wqt, wkt, wvt,
                                     bQ, bK, bV, qbf, kbf, vtb, QSCL);

  attn_k<<<dim3(64, 8), blk, 0, stream>>>(qbf, kbf, vtb, Kms, ctx);

  gemmo_k<<<256, blk, 0, stream>>>(ctx, wot, bO, xbf, Qin);

  ln_k<<<4096, blk, 0, stream>>>(xbf, lng, lnb, (float*)d_out);
}

// Round 11
// 167.615 us; speedup vs baseline: 1.0914x; 1.0914x over previous
//
#include <hip/hip_runtime.h>
#include <hip/hip_bf16.h>
#include <stdint.h>

// Problem constants
#define Bn 4
#define Ln 1024
#define Dn 1024
#define Hn 16
#define DHn 64
#define Mn (Bn*Ln)   // 4096 tokens

typedef __attribute__((ext_vector_type(8))) short short8v;   // 8 x bf16 (4 VGPRs)
typedef __attribute__((ext_vector_type(4))) float floatx4;   // MFMA accumulator

__device__ __forceinline__ unsigned short f2b(float f){
  union { float f; unsigned u; } v; v.f = f;
  unsigned r = (v.u + 0x7FFFu + ((v.u >> 16) & 1u)) >> 16;  // RNE
  return (unsigned short)r;
}
__device__ __forceinline__ unsigned short f2b_fast(float f){
  __hip_bfloat16 h = __float2bfloat16(f);   // compiler-native cvt (RNE)
  return *reinterpret_cast<unsigned short*>(&h);
}

// global -> LDS direct copy, 16B per lane.
typedef const unsigned __attribute__((address_space(1)))* gas1_t;
typedef unsigned __attribute__((address_space(3)))* las3_t;
__device__ __forceinline__ void gload16(const void* g, void* l){
  __builtin_amdgcn_global_load_lds((gas1_t)(uintptr_t)g, (las3_t)(uintptr_t)l, 16, 0, 0);
}

// ---------------------------------------------------------------------------
// fp32 -> bf16 streaming convert, all three inputs in one launch
// ---------------------------------------------------------------------------
__global__ __launch_bounds__(256) void tobf16x3_k(const float* __restrict__ x0,
    const float* __restrict__ x1, const float* __restrict__ x2,
    unsigned short* __restrict__ o0, unsigned short* __restrict__ o1,
    unsigned short* __restrict__ o2)
{
  const int i = blockIdx.x * 256 + threadIdx.x;      // [0, 3*2^20)
  const int sel = i >> 20, idx = i & 0xFFFFF;
  const float* x = sel == 0 ? x0 : (sel == 1 ? x1 : x2);
  unsigned short* o = sel == 0 ? o0 : (sel == 1 ? o1 : o2);
  float4 v = reinterpret_cast<const float4*>(x)[idx];
  union { unsigned short u[4]; uint2 q; } p;
  p.u[0] = f2b(v.x); p.u[1] = f2b(v.y); p.u[2] = f2b(v.z); p.u[3] = f2b(v.w);
  reinterpret_cast<uint2*>(o)[idx] = p.q;
}

// ---------------------------------------------------------------------------
// Weight transpose + fp32->bf16 convert, all 4 weights in one launch
// ---------------------------------------------------------------------------
__global__ __launch_bounds__(256) void wconv4_k(const float* __restrict__ W0,
    const float* __restrict__ W1, const float* __restrict__ W2,
    const float* __restrict__ W3, unsigned short* __restrict__ Wt0,
    unsigned short* __restrict__ Wt1, unsigned short* __restrict__ Wt2,
    unsigned short* __restrict__ Wt3)
{
  const float* W; unsigned short* Wt;
  switch (blockIdx.z){
    case 0: W = W0; Wt = Wt0; break;
    case 1: W = W1; Wt = Wt1; break;
    case 2: W = W2; Wt = Wt2; break;
    default: W = W3; Wt = Wt3; break;
  }
  __shared__ float tile[64][65];
  const int nb = blockIdx.x * 64, kb = blockIdx.y * 64;
  const int tx = threadIdx.x & 63, ty = threadIdx.x >> 6;  // ty 0..3
  #pragma unroll
  for (int r = 0; r < 64; r += 4)
    tile[r + ty][tx] = W[(size_t)(kb + r + ty) * 1024 + nb + tx];
  __syncthreads();
  #pragma unroll
  for (int r = 0; r < 64; r += 4)
    Wt[(size_t)(nb + r + ty) * 1024 + kb + tx] = f2b(tile[tx][r + ty]);
}

// ---------------------------------------------------------------------------
// GEMM core v6: 128x128 tile, acc[4][4]/wave. LDS-BW-bound diagnosis (r10):
// 96KB LDS traffic per block-K-step saturated the LDS pipe (2900cyc/step).
// Fix: B operand loaded DIRECT global->VGPR (weights are L2-hot; per-lane
// pattern = the same addresses the gload src used; 64B/row coalescing).
// LDS now carries only A: 16KB write + 32KB read per block-K-step (48KB,
// half of before). B loads are issued at loop top (overlap barrier+stage).
//  MODE 0: out bf16 [B,H,L,DH]
//  MODE 2: out bf16 [B,H,DH,L] via XOR-swizzled LDS transpose (16B stores)
//  MODE 3: out fp32 [M,D] = acc + bias + resid (pre-layernorm x)
// ---------------------------------------------------------------------------
template<int MODE>
__device__ __forceinline__ void gemm_core(const unsigned short* __restrict__ Ab,
    const unsigned short* __restrict__ Btp, const float* __restrict__ bias,
    void* __restrict__ outp, const float* __restrict__ resid, float scale,
    unsigned short* lds, int nt, int mt)
{
  unsigned short* ldsA = lds;           // 16 KB staging (A only)
  const int tid = threadIdx.x;
  const int lane = tid & 63, wave = tid >> 6;
  const int wr = wave >> 1, wc = wave & 1;
  const int lg = lane >> 4, lr = lane & 15;
  const int m0 = mt * 128, n0 = nt * 128;

  // A: 128x64 tile = 1024 16B chunks; 4 gload16/thread. chunk c -> row,col.
  const unsigned short* gA[4];
  #pragma unroll
  for (int i = 0; i < 4; i++){
    int c = (wave * 4 + i) * 64 + lane;            // 0..1023 chunks
    int ks = c >> 9, r16 = (c >> 6) & 7, lhi = (c >> 4) & 3, lrr = c & 15;
    int row = r16 * 16 + lrr, col = ks * 32 + lhi * 8;
    gA[i] = Ab + (size_t)(m0 + row) * 1024 + col;
  }
  // B: direct per-lane fragment pointers (row n0+wc*64+n*16+lr, col lg*8)
  const unsigned short* gB[4];
  #pragma unroll
  for (int n = 0; n < 4; n++)
    gB[n] = Btp + (size_t)(n0 + wc * 64 + n * 16 + lr) * 1024 + lg * 8;

  floatx4 acc[4][4] = {};

  for (int kb = 0; kb < 16; kb++){
    // B fragments for this K-step: 8 x global_load_dwordx4 -> VGPR (L2-hot)
    short8v bfr[2][4];
    #pragma unroll
    for (int ks = 0; ks < 2; ks++)
      #pragma unroll
      for (int n = 0; n < 4; n++)
        bfr[ks][n] = *reinterpret_cast<const short8v*>(gB[n] + kb * 64 + ks * 32);
    if (kb) __syncthreads();           // WAR: prev K-step's LDS reads done
    #pragma unroll
    for (int i = 0; i < 4; i++)
      gload16(gA[i] + kb * 64, &ldsA[(wave * 4 + i) * 512]);
    asm volatile("s_waitcnt vmcnt(0)" ::: "memory");   // A staged (+B landed)
    __syncthreads();                   // RAW: tile visible to all waves
    #pragma unroll
    for (int ks = 0; ks < 2; ks++){
      short8v af[4];
      #pragma unroll
      for (int m = 0; m < 4; m++)
        af[m] = *reinterpret_cast<const short8v*>(&ldsA[((ks * 8 + wr * 4 + m) * 64 + lane) * 8]);
      #pragma unroll
      for (int m = 0; m < 4; m++)
        #pragma unroll
        for (int n = 0; n < 4; n++)
          acc[m][n] = __builtin_amdgcn_mfma_f32_16x16x32_bf16(af[m], bfr[ks][n], acc[m][n], 0, 0, 0);
    }
  }

  if constexpr (MODE == 2){
    // transpose epilogue: stage C^T (bf16) in LDS with XOR swizzle, then
    // write V^T rows as contiguous 16B chunks.
    __syncthreads();                   // K-loop LDS reads done
    #pragma unroll
    for (int n = 0; n < 4; n++){
      const int gn_l = wc * 64 + n * 16 + lr;        // d-dim local row
      const float bb = bias[n0 + gn_l];
      const int X = (gn_l & 7) << 3;
      #pragma unroll
      for (int m = 0; m < 4; m++){
        const int gm_l = wr * 64 + m * 16 + lg * 4;  // token local col
        union { unsigned short u[4]; uint2 q; } pk;
        #pragma unroll
        for (int r = 0; r < 4; r++) pk.u[r] = f2b((acc[m][n][r] + bb) * scale);
        *reinterpret_cast<uint2*>(&lds[gn_l * 128 + (gm_l ^ X)]) = pk.q;
      }
    }
    __syncthreads();
    const int b = m0 >> 10, l0 = m0 & 1023;
    const int row = tid >> 1, colb = (tid & 1) * 64;  // row: d-dim, col: token
    const int h2 = (n0 + row) >> 6, d = (n0 + row) & 63;
    unsigned short* obase = (unsigned short*)outp +
        (((size_t)(b * Hn + h2)) * DHn + d) * Ln + l0 + colb;
    const int XR = (row & 7) << 3;
    #pragma unroll
    for (int g = 0; g < 8; g++){
      short8v v = *reinterpret_cast<const short8v*>(&lds[row * 128 + ((colb + g * 8) ^ XR)]);
      *reinterpret_cast<short8v*>(obase + g * 8) = v;
    }
  } else {
    #pragma unroll
    for (int n = 0; n < 4; n++){
      const int gn = n0 + wc * 64 + n * 16 + lr;
      const float bb = bias[gn];
      #pragma unroll
      for (int m = 0; m < 4; m++){
        const int gm0 = m0 + wr * 64 + m * 16 + lg * 4;
        #pragma unroll
        for (int r = 0; r < 4; r++){
          const int gm = gm0 + r;
          float v = (acc[m][n][r] + bb) * scale;
          if constexpr (MODE == 0){
            unsigned short* o = (unsigned short*)outp;
            int b = gm >> 10, l = gm & 1023, h2 = gn >> 6, d = gn & 63;
            o[(((size_t)(b * Hn + h2)) * Ln + l) * DHn + d] = f2b(v);
          } else {
            float* o = (float*)outp;
            o[(size_t)gm * Dn + gn] = v + resid[(size_t)gm * Dn + gn];
          }
        }
      }
    }
  }
}

// Fused Q/K/V projections: 768 blocks = 3/CU. XCD-panel affinity, z interleaved.
__global__ __launch_bounds__(256) void gemmqkv_k(
    const unsigned short* __restrict__ A0, const unsigned short* __restrict__ A1,
    const unsigned short* __restrict__ A2, const unsigned short* __restrict__ W0,
    const unsigned short* __restrict__ W1, const unsigned short* __restrict__ W2,
    const float* __restrict__ b0, const float* __restrict__ b1,
    const float* __restrict__ b2, unsigned short* __restrict__ o0,
    unsigned short* __restrict__ o1, unsigned short* __restrict__ o2, float qscl)
{
  __shared__ __align__(16) unsigned short lds[16384];   // 32KB (A stage + epilogue)
  const int bid = blockIdx.x;
  const int xcd = bid & 7, k = bid >> 3;       // k: 0..95
  const int panel = (k >> 3) * 8 + xcd;        // 0..95; 12 panels/XCD, 4 per z
  const int nt = k & 7;                        // 0..7
  const int mt = panel & 31, z = panel >> 5;
  if (z == 0)
    gemm_core<0>(A0, W0, b0, o0, nullptr, qscl, lds, nt, mt);
  else if (z == 1)
    gemm_core<0>(A1, W1, b1, o1, nullptr, 1.f, lds, nt, mt);
  else
    gemm_core<2>(A2, W2, b2, o2, nullptr, 1.f, lds, nt, mt);
}

// O projection + residual: 256 blocks (32 mt x 8 nt), XCD affinity.
__global__ __launch_bounds__(256) void gemmo_k(const unsigned short* __restrict__ Ab,
    const unsigned short* __restrict__ W, const float* __restrict__ bias,
    float* __restrict__ out, const float* __restrict__ resid)
{
  __shared__ __align__(16) unsigned short lds[16384];
  const int bid = blockIdx.x;
  const int xcd = bid & 7, k = bid >> 3;       // k: 0..31
  const int mt = (k >> 3) * 8 + xcd;
  const int nt = k & 7;
  gemm_core<3>(Ab, W, bias, out, resid, 1.f, lds, nt, mt);
}

// ---------------------------------------------------------------------------
// Flash attention v6 (round-9, unchanged): grid (B*H, L/128), 4 waves x 32
// q-rows, KVBLK=64, no-max exp2 softmax, deferred denominator, dbuf K/V via
// global_load_lds, mask prefetch.
// ---------------------------------------------------------------------------
__global__ __launch_bounds__(256) void attn_k(const unsigned short* __restrict__ qb,
    const unsigned short* __restrict__ kbf, const unsigned short* __restrict__ vtb,
    const int* __restrict__ kmask, unsigned short* __restrict__ ctx)
{
  const int bh = blockIdx.x;        // 0..63
  const int qt = blockIdx.y;        // 0..7
  const int b = bh >> 4, h = bh & 15;
  const int tid = threadIdx.x;
  const int w = tid >> 6, lane = tid & 63;
  const int lg = lane >> 4, lr = lane & 15;

  const unsigned short* qp = qb  + (size_t)bh * Ln * DHn;
  const unsigned short* kp = kbf + (size_t)bh * Ln * DHn;
  const unsigned short* vp = vtb + (size_t)bh * DHn * Ln;
  const int q0 = qt * 128 + w * 32;

  __shared__ __align__(16) unsigned short ldsK[2][4096];   // 2 x 8KB
  __shared__ __align__(16) unsigned short ldsV[2][4096];
  __shared__ __align__(16) unsigned short plds[4][32][72]; // per-wave P (32 q-rows)

  const unsigned short* gK[2];
  const unsigned short* gV[2];
  #pragma unroll
  for (int i = 0; i < 2; i++){
    int bc = w * 2 + i;             // 0..7
    int ks = bc >> 2, j = bc & 3;
    int row = j * 16 + lr, col = ks * 32 + lg * 8;
    gK[i] = kp + (size_t)row * DHn + col;   // + t*4096 per tile
    gV[i] = vp + (size_t)row * Ln  + col;   // + t*64 per tile
  }

  short8v aq[2][2];                  // [qfrag][ks]
  #pragma unroll
  for (int f = 0; f < 2; f++)
    #pragma unroll
    for (int ks = 0; ks < 2; ks++)
      aq[f][ks] = *reinterpret_cast<const short8v*>(
          qp + (size_t)(q0 + f * 16 + lr) * DHn + ks * 32 + lg * 8);

  floatx4 accO[2][4] = {};
  float lsacc[2][4] = {{0.f,0.f,0.f,0.f},{0.f,0.f,0.f,0.f}};

  const int* mrow = kmask + b * Ln;
  int mkA[4], mkB[4];

  #pragma unroll
  for (int i = 0; i < 2; i++){
    gload16(gK[i], &ldsK[0][(w * 2 + i) * 512]);
    gload16(gV[i], &ldsV[0][(w * 2 + i) * 512]);
  }
  #pragma unroll
  for (int j = 0; j < 4; j++) mkA[j] = mrow[j * 16 + lr];

  for (int t = 0; t < 16; t++){
    const int cur = t & 1;
    asm volatile("s_waitcnt vmcnt(0)" ::: "memory");
    __syncthreads();
    if (t < 15){
      #pragma unroll
      for (int i = 0; i < 2; i++){
        gload16(gK[i] + (size_t)(t + 1) * 4096, &ldsK[cur ^ 1][(w * 2 + i) * 512]);
        gload16(gV[i] + (size_t)(t + 1) * 64,   &ldsV[cur ^ 1][(w * 2 + i) * 512]);
      }
      #pragma unroll
      for (int j = 0; j < 4; j++) mkB[j] = mrow[(t + 1) * 64 + j * 16 + lr];
    }

    floatx4 s[2][4] = {};
    #pragma unroll
    for (int ks = 0; ks < 2; ks++)
      #pragma unroll
      for (int j = 0; j < 4; j++){
        short8v bk = *reinterpret_cast<const short8v*>(&ldsK[cur][((ks * 4 + j) * 64 + lane) * 8]);
        s[0][j] = __builtin_amdgcn_mfma_f32_16x16x32_bf16(aq[0][ks], bk, s[0][j], 0, 0, 0);
        s[1][j] = __builtin_amdgcn_mfma_f32_16x16x32_bf16(aq[1][ks], bk, s[1][j], 0, 0, 0);
      }
    if (__all(mkA[0] > 0 && mkA[1] > 0 && mkA[2] > 0 && mkA[3] > 0)){
      #pragma unroll
      for (int f = 0; f < 2; f++)
        #pragma unroll
        for (int j = 0; j < 4; j++)
          #pragma unroll
          for (int r = 0; r < 4; r++){
            float p = __builtin_amdgcn_exp2f(s[f][j][r]);
            lsacc[f][r] += p;
            plds[w][f * 16 + lg * 4 + r][j * 16 + lr] = f2b_fast(p);
          }
    } else {
      #pragma unroll
      for (int j = 0; j < 4; j++){
        const float madd = mkA[j] > 0 ? 0.f : -1e9f;
        #pragma unroll
        for (int f = 0; f < 2; f++)
          #pragma unroll
          for (int r = 0; r < 4; r++){
            float p = __builtin_amdgcn_exp2f(s[f][j][r] + madd);
            lsacc[f][r] += p;
            plds[w][f * 16 + lg * 4 + r][j * 16 + lr] = f2b_fast(p);
          }
      }
    }
    #pragma unroll
    for (int ks = 0; ks < 2; ks++){
      short8v pa0 = *reinterpret_cast<const short8v*>(&plds[w][lr][ks * 32 + lg * 8]);
      short8v pa1 = *reinterpret_cast<const short8v*>(&plds[w][16 + lr][ks * 32 + lg * 8]);
      #pragma unroll
      for (int n = 0; n < 4; n++){
        short8v bv = *reinterpret_cast<const short8v*>(&ldsV[cur][((ks * 4 + n) * 64 + lane) * 8]);
        accO[0][n] = __builtin_amdgcn_mfma_f32_16x16x32_bf16(pa0, bv, accO[0][n], 0, 0, 0);
        accO[1][n] = __builtin_amdgcn_mfma_f32_16x16x32_bf16(pa1, bv, accO[1][n], 0, 0, 0);
      }
    }
    #pragma unroll
    for (int j = 0; j < 4; j++) mkA[j] = mkB[j];
  }

  #pragma unroll
  for (int f = 0; f < 2; f++)
    #pragma unroll
    for (int r = 0; r < 4; r++){
      lsacc[f][r] += __shfl_xor(lsacc[f][r], 1, 64);
      lsacc[f][r] += __shfl_xor(lsacc[f][r], 2, 64);
      lsacc[f][r] += __shfl_xor(lsacc[f][r], 4, 64);
      lsacc[f][r] += __shfl_xor(lsacc[f][r], 8, 64);
      lsacc[f][r] = 1.f / fmaxf(lsacc[f][r], 1e-20f);
    }
  #pragma unroll
  for (int f = 0; f < 2; f++)
    #pragma unroll
    for (int n = 0; n < 4; n++)
      #pragma unroll
      for (int r = 0; r < 4; r++){
        float o = accO[f][n][r] * lsacc[f][r];
        int q = q0 + f * 16 + lg * 4 + r;
        ctx[((size_t)(b * Ln + q)) * Dn + h * DHn + n * 16 + lr] = f2b_fast(o);
      }
}

// ---------------------------------------------------------------------------
// LayerNorm: one block per row of x[4096][1024] fp32 -> out fp32
// ---------------------------------------------------------------------------
__global__ __launch_bounds__(256) void ln_k(const float* __restrict__ x,
    const float* __restrict__ g, const float* __restrict__ bt, float* __restrict__ out)
{
  const int row = blockIdx.x;
  const int tid = threadIdx.x;
  float4 v = *reinterpret_cast<const float4*>(x + (size_t)row * 1024 + tid * 4);
  float s  = v.x + v.y + v.z + v.w;
  float sq = v.x * v.x + v.y * v.y + v.z * v.z + v.w * v.w;
  #pragma unroll
  for (int off = 32; off >= 1; off >>= 1){
    s  += __shfl_xor(s, off, 64);
    sq += __shfl_xor(sq, off, 64);
  }
  __shared__ float psm[4], pqm[4];
  const int w = tid >> 6;
  if ((tid & 63) == 0){ psm[w] = s; pqm[w] = sq; }
  __syncthreads();
  s  = psm[0] + psm[1] + psm[2] + psm[3];
  sq = pqm[0] + pqm[1] + pqm[2] + pqm[3];
  const float mean = s * (1.f / 1024.f);
  const float var  = sq * (1.f / 1024.f) - mean * mean;
  const float inv  = rsqrtf(var + 1e-5f);
  float4 gg = *reinterpret_cast<const float4*>(g  + tid * 4);
  float4 bb = *reinterpret_cast<const float4*>(bt + tid * 4);
  float4 o;
  o.x = (v.x - mean) * inv * gg.x + bb.x;
  o.y = (v.y - mean) * inv * gg.y + bb.y;
  o.z = (v.z - mean) * inv * gg.z + bb.z;
  o.w = (v.w - mean) * inv * gg.w + bb.w;
  *reinterpret_cast<float4*>(out + (size_t)row * 1024 + tid * 4) = o;
}

// ---------------------------------------------------------------------------
extern "C" void kernel_launch(void* const* d_in, const int* in_sizes, int n_in,
                              void* d_out, int out_size, void* d_ws, size_t ws_size,
                              hipStream_t stream)
{
  const float* Qin = (const float*)d_in[0];
  const float* Kin = (const float*)d_in[1];
  const float* Vin = (const float*)d_in[2];
  const int*   Kms = (const int*)d_in[3];
  const float* WQ  = (const float*)d_in[4];
  const float* bQ  = (const float*)d_in[5];
  const float* WK  = (const float*)d_in[6];
  const float* bK  = (const float*)d_in[7];
  const float* WV  = (const float*)d_in[8];
  const float* bV  = (const float*)d_in[9];
  const float* WO  = (const float*)d_in[10];
  const float* bO  = (const float*)d_in[11];
  const float* lng = (const float*)d_in[12];
  const float* lnb = (const float*)d_in[13];

  char* ws = (char*)d_ws;
  const size_t MB = 1024u * 1024u;
  unsigned short* wqt = (unsigned short*)(ws + 0 * MB);    // 1024x1024 bf16 = 2MB
  unsigned short* wkt = (unsigned short*)(ws + 2 * MB);
  unsigned short* wvt = (unsigned short*)(ws + 4 * MB);
  unsigned short* wot = (unsigned short*)(ws + 6 * MB);
  unsigned short* qbf = (unsigned short*)(ws + 8 * MB);    // [B,H,L,DH] bf16 = 8MB
  unsigned short* kbf = (unsigned short*)(ws + 16 * MB);
  unsigned short* vtb = (unsigned short*)(ws + 24 * MB);   // [B,H,DH,L]
  unsigned short* ctx = (unsigned short*)(ws + 32 * MB);   // [B,L,D] bf16
  float*          xbf = (float*)(ws + 40 * MB);            // [M,D] fp32 = 16MB
  // bf16 copies of Q,K,V inputs -- alias regions that are dead until later:
  unsigned short* cv0 = (unsigned short*)(ws + 32 * MB);   // aliases ctx (written later by attn)
  unsigned short* cv1 = (unsigned short*)(ws + 40 * MB);   // aliases xbf[0:8MB] (written later by gemmo)
  unsigned short* cv2 = (unsigned short*)(ws + 48 * MB);   // aliases xbf[8:16MB]

  dim3 blk(256);
  wconv4_k<<<dim3(16, 16, 4), blk, 0, stream>>>(WQ, WK, WV, WO, wqt, wkt, wvt, wot);
  tobf16x3_k<<<12288, blk, 0, stream>>>(Qin, Kin, Vin, cv0, cv1, cv2);

  const float QSCL = 0.125f * 1.44269504088896f;  // fold 1/sqrt(dh) * log2(e) into q
  gemmqkv_k<<<768, blk, 0, stream>>>(cv0, cv1, cv2, wqt, wkt, wvt,
                                     bQ, bK, bV, qbf, kbf, vtb, QSCL);

  attn_k<<<dim3(64, 8), blk, 0, stream>>>(qbf, kbf, vtb, Kms, ctx);

  gemmo_k<<<256, blk, 0, stream>>>(ctx, wot, bO, xbf, Qin);

  ln_k<<<4096, blk, 0, stream>>>(xbf, lng, lnb, (float*)d_out);
}

// Round 12
// 137.459 us; speedup vs baseline: 1.3308x; 1.2194x over previous
//
#include <hip/hip_runtime.h>
#include <hip/hip_bf16.h>
#include <stdint.h>

// Problem constants
#define Bn 4
#define Ln 1024
#define Dn 1024
#define Hn 16
#define DHn 64
#define Mn (Bn*Ln)   // 4096 tokens

typedef __attribute__((ext_vector_type(8))) short short8v;   // 8 x bf16 (4 VGPRs)
typedef __attribute__((ext_vector_type(4))) float floatx4;   // MFMA accumulator

__device__ __forceinline__ unsigned short f2b(float f){
  union { float f; unsigned u; } v; v.f = f;
  unsigned r = (v.u + 0x7FFFu + ((v.u >> 16) & 1u)) >> 16;  // RNE
  return (unsigned short)r;
}
__device__ __forceinline__ unsigned short f2b_fast(float f){
  __hip_bfloat16 h = __float2bfloat16(f);   // compiler-native cvt (RNE)
  return *reinterpret_cast<unsigned short*>(&h);
}

// global -> LDS direct copy, 16B per lane.
typedef const unsigned __attribute__((address_space(1)))* gas1_t;
typedef unsigned __attribute__((address_space(3)))* las3_t;
__device__ __forceinline__ void gload16(const void* g, void* l){
  __builtin_amdgcn_global_load_lds((gas1_t)(uintptr_t)g, (las3_t)(uintptr_t)l, 16, 0, 0);
}

// ---------------------------------------------------------------------------
// fp32 -> bf16 streaming convert, all three inputs in one launch
// ---------------------------------------------------------------------------
__global__ __launch_bounds__(256) void tobf16x3_k(const float* __restrict__ x0,
    const float* __restrict__ x1, const float* __restrict__ x2,
    unsigned short* __restrict__ o0, unsigned short* __restrict__ o1,
    unsigned short* __restrict__ o2)
{
  const int i = blockIdx.x * 256 + threadIdx.x;      // [0, 3*2^20)
  const int sel = i >> 20, idx = i & 0xFFFFF;
  const float* x = sel == 0 ? x0 : (sel == 1 ? x1 : x2);
  unsigned short* o = sel == 0 ? o0 : (sel == 1 ? o1 : o2);
  float4 v = reinterpret_cast<const float4*>(x)[idx];
  union { unsigned short u[4]; uint2 q; } p;
  p.u[0] = f2b(v.x); p.u[1] = f2b(v.y); p.u[2] = f2b(v.z); p.u[3] = f2b(v.w);
  reinterpret_cast<uint2*>(o)[idx] = p.q;
}

// ---------------------------------------------------------------------------
// Weight transpose + fp32->bf16 convert, all 4 weights in one launch
// ---------------------------------------------------------------------------
__global__ __launch_bounds__(256) void wconv4_k(const float* __restrict__ W0,
    const float* __restrict__ W1, const float* __restrict__ W2,
    const float* __restrict__ W3, unsigned short* __restrict__ Wt0,
    unsigned short* __restrict__ Wt1, unsigned short* __restrict__ Wt2,
    unsigned short* __restrict__ Wt3)
{
  const float* W; unsigned short* Wt;
  switch (blockIdx.z){
    case 0: W = W0; Wt = Wt0; break;
    case 1: W = W1; Wt = Wt1; break;
    case 2: W = W2; Wt = Wt2; break;
    default: W = W3; Wt = Wt3; break;
  }
  __shared__ float tile[64][65];
  const int nb = blockIdx.x * 64, kb = blockIdx.y * 64;
  const int tx = threadIdx.x & 63, ty = threadIdx.x >> 6;  // ty 0..3
  #pragma unroll
  for (int r = 0; r < 64; r += 4)
    tile[r + ty][tx] = W[(size_t)(kb + r + ty) * 1024 + nb + tx];
  __syncthreads();
  #pragma unroll
  for (int r = 0; r < 64; r += 4)
    Wt[(size_t)(nb + r + ty) * 1024 + kb + tx] = f2b(tile[tx][r + ty]);
}

// ---------------------------------------------------------------------------
// GEMM core v7: 128x128 tile, acc[4][4]/wave, DEPTH-2 pipeline.
// Diagnosis (r7-r11): loads run at L3 latency (~500-900cy, working set > 4MB
// L2/XCD); __syncthreads drains vmcnt -> zero prefetch depth (r7/r9); depth-1
// covers only ~300cy (r8). Fix: 3 LDS buffers (96KB), per K-step:
//   { issue T(k+2) -> s_waitcnt vmcnt(16)  [T(k) done; T(k+1),T(k+2) in
//     flight = 2 compute phases ~1240cy of cover] -> raw s_barrier ->
//     compute T(k) -> raw s_barrier }
// WAR safe: T(k+2) targets buf[(k+2)%3] == buf[(k-1)%3], whose reads all
// completed before the previous trailing barrier. vmcnt never drains to 0
// mid-loop. 1 block/CU (LDS-bound) -- hiding is in-wave by construction.
//  MODE 0: out bf16 [B,H,L,DH]
//  MODE 2: out bf16 [B,H,DH,L] via XOR-swizzled LDS transpose (16B stores)
//  MODE 3: out fp32 [M,D] = acc + bias + resid (pre-layernorm x)
// ---------------------------------------------------------------------------
template<int MODE>
__device__ __forceinline__ void gemm_core(const unsigned short* __restrict__ Ab,
    const unsigned short* __restrict__ Btp, const float* __restrict__ bias,
    void* __restrict__ outp, const float* __restrict__ resid, float scale,
    unsigned short* lds, int nt, int mt)
{
  const int tid = threadIdx.x;
  const int lane = tid & 63, wave = tid >> 6;
  const int wr = wave >> 1, wc = wave & 1;
  const int lg = lane >> 4, lr = lane & 15;
  const int m0 = mt * 128, n0 = nt * 128;

  // per-lane global source addrs: 4 A-chunks + 4 B-chunks per wave per tile
  const unsigned short* gA[4];
  const unsigned short* gB[4];
  #pragma unroll
  for (int i = 0; i < 4; i++){
    int c = (wave * 4 + i) * 64 + lane;            // 0..1023 chunks
    int ks = c >> 9, r16 = (c >> 6) & 7, lhi = (c >> 4) & 3, lrr = c & 15;
    int row = r16 * 16 + lrr, col = ks * 32 + lhi * 8;
    gA[i] = Ab  + (size_t)(m0 + row) * 1024 + col;
    gB[i] = Btp + (size_t)(n0 + row) * 1024 + col;
  }

  floatx4 acc[4][4] = {};

  // buffer t%3: A at (t%3)*16384, B at +8192 (ushort units)
  auto issue = [&](int t){
    unsigned short* bufA = lds + (t % 3) * 16384;
    unsigned short* bufB = bufA + 8192;
    #pragma unroll
    for (int i = 0; i < 4; i++){
      gload16(gA[i] + t * 64, &bufA[(wave * 4 + i) * 512]);
      gload16(gB[i] + t * 64, &bufB[(wave * 4 + i) * 512]);
    }
  };

  issue(0);
  issue(1);

  for (int kb = 0; kb < 16; kb++){
    unsigned short* bufA = lds + (kb % 3) * 16384;
    unsigned short* bufB = bufA + 8192;
    if (kb < 14){
      issue(kb + 2);                                      // depth-2 prefetch
      asm volatile("s_waitcnt vmcnt(16)" ::: "memory");   // T(kb) landed
    } else if (kb == 14){
      asm volatile("s_waitcnt vmcnt(8)" ::: "memory");    // T14 landed
    } else {
      asm volatile("s_waitcnt vmcnt(0)" ::: "memory");    // T15 landed
    }
    __builtin_amdgcn_s_barrier();          // raw: prefetch stays in flight
    __builtin_amdgcn_sched_barrier(0);     // pin ds_reads below barrier
    #pragma unroll
    for (int ks = 0; ks < 2; ks++){
      short8v af[4], bfr[4];
      #pragma unroll
      for (int m = 0; m < 4; m++)
        af[m] = *reinterpret_cast<const short8v*>(&bufA[((ks * 8 + wr * 4 + m) * 64 + lane) * 8]);
      #pragma unroll
      for (int n = 0; n < 4; n++)
        bfr[n] = *reinterpret_cast<const short8v*>(&bufB[((ks * 8 + wc * 4 + n) * 64 + lane) * 8]);
      #pragma unroll
      for (int m = 0; m < 4; m++)
        #pragma unroll
        for (int n = 0; n < 4; n++)
          acc[m][n] = __builtin_amdgcn_mfma_f32_16x16x32_bf16(af[m], bfr[n], acc[m][n], 0, 0, 0);
    }
    __builtin_amdgcn_sched_barrier(0);     // pin ds_reads above barrier
    __builtin_amdgcn_s_barrier();          // buf[(kb)%3] reads done (WAR)
  }

  if constexpr (MODE == 2){
    // transpose epilogue: stage C^T (bf16) in LDS with XOR swizzle, then
    // write V^T rows as contiguous 16B chunks.
    __syncthreads();                   // all waves out of the K-loop
    #pragma unroll
    for (int n = 0; n < 4; n++){
      const int gn_l = wc * 64 + n * 16 + lr;        // d-dim local row
      const float bb = bias[n0 + gn_l];
      const int X = (gn_l & 7) << 3;
      #pragma unroll
      for (int m = 0; m < 4; m++){
        const int gm_l = wr * 64 + m * 16 + lg * 4;  // token local col
        union { unsigned short u[4]; uint2 q; } pk;
        #pragma unroll
        for (int r = 0; r < 4; r++) pk.u[r] = f2b((acc[m][n][r] + bb) * scale);
        *reinterpret_cast<uint2*>(&lds[gn_l * 128 + (gm_l ^ X)]) = pk.q;
      }
    }
    __syncthreads();
    const int b = m0 >> 10, l0 = m0 & 1023;
    const int row = tid >> 1, colb = (tid & 1) * 64;  // row: d-dim, col: token
    const int h2 = (n0 + row) >> 6, d = (n0 + row) & 63;
    unsigned short* obase = (unsigned short*)outp +
        (((size_t)(b * Hn + h2)) * DHn + d) * Ln + l0 + colb;
    const int XR = (row & 7) << 3;
    #pragma unroll
    for (int g = 0; g < 8; g++){
      short8v v = *reinterpret_cast<const short8v*>(&lds[row * 128 + ((colb + g * 8) ^ XR)]);
      *reinterpret_cast<short8v*>(obase + g * 8) = v;
    }
  } else {
    #pragma unroll
    for (int n = 0; n < 4; n++){
      const int gn = n0 + wc * 64 + n * 16 + lr;
      const float bb = bias[gn];
      #pragma unroll
      for (int m = 0; m < 4; m++){
        const int gm0 = m0 + wr * 64 + m * 16 + lg * 4;
        #pragma unroll
        for (int r = 0; r < 4; r++){
          const int gm = gm0 + r;
          float v = (acc[m][n][r] + bb) * scale;
          if constexpr (MODE == 0){
            unsigned short* o = (unsigned short*)outp;
            int b = gm >> 10, l = gm & 1023, h2 = gn >> 6, d = gn & 63;
            o[(((size_t)(b * Hn + h2)) * Ln + l) * DHn + d] = f2b(v);
          } else {
            float* o = (float*)outp;
            o[(size_t)gm * Dn + gn] = v + resid[(size_t)gm * Dn + gn];
          }
        }
      }
    }
  }
}

// Fused Q/K/V projections: 768 blocks, 1 block/CU (96KB LDS), 3 rounds.
// r7 panel mapping: each XCD owns 12 consecutive panels (FETCH ~24MB).
__global__ __launch_bounds__(256) void gemmqkv_k(
    const unsigned short* __restrict__ A0, const unsigned short* __restrict__ A1,
    const unsigned short* __restrict__ A2, const unsigned short* __restrict__ W0,
    const unsigned short* __restrict__ W1, const unsigned short* __restrict__ W2,
    const float* __restrict__ b0, const float* __restrict__ b1,
    const float* __restrict__ b2, unsigned short* __restrict__ o0,
    unsigned short* __restrict__ o1, unsigned short* __restrict__ o2, float qscl)
{
  __shared__ __align__(16) unsigned short lds[49152];   // 96KB: 3 x (16KB A + 16KB B)
  const int bid = blockIdx.x;
  const int xcd = bid & 7, k = bid >> 3;       // k: 0..95
  const int panel = xcd * 12 + (k >> 3);       // 0..95, XCD-contiguous
  const int nt = k & 7;                        // 0..7
  const int mt = panel & 31, z = panel >> 5;   // panel = z*32 + mt
  if (z == 0)
    gemm_core<0>(A0, W0, b0, o0, nullptr, qscl, lds, nt, mt);
  else if (z == 1)
    gemm_core<0>(A1, W1, b1, o1, nullptr, 1.f, lds, nt, mt);
  else
    gemm_core<2>(A2, W2, b2, o2, nullptr, 1.f, lds, nt, mt);
}

// O projection + residual: 256 blocks (1 round), XCD affinity.
__global__ __launch_bounds__(256) void gemmo_k(const unsigned short* __restrict__ Ab,
    const unsigned short* __restrict__ W, const float* __restrict__ bias,
    float* __restrict__ out, const float* __restrict__ resid)
{
  __shared__ __align__(16) unsigned short lds[49152];
  const int bid = blockIdx.x;
  const int xcd = bid & 7, k = bid >> 3;       // k: 0..31
  const int mt = xcd * 4 + (k >> 3);
  const int nt = k & 7;
  gemm_core<3>(Ab, W, bias, out, resid, 1.f, lds, nt, mt);
}

// ---------------------------------------------------------------------------
// Flash attention v6 (round-9, unchanged): grid (B*H, L/128), 4 waves x 32
// q-rows, KVBLK=64, no-max exp2 softmax, deferred denominator, dbuf K/V via
// global_load_lds, mask prefetch.
// ---------------------------------------------------------------------------
__global__ __launch_bounds__(256) void attn_k(const unsigned short* __restrict__ qb,
    const unsigned short* __restrict__ kbf, const unsigned short* __restrict__ vtb,
    const int* __restrict__ kmask, unsigned short* __restrict__ ctx)
{
  const int bh = blockIdx.x;        // 0..63
  const int qt = blockIdx.y;        // 0..7
  const int b = bh >> 4, h = bh & 15;
  const int tid = threadIdx.x;
  const int w = tid >> 6, lane = tid & 63;
  const int lg = lane >> 4, lr = lane & 15;

  const unsigned short* qp = qb  + (size_t)bh * Ln * DHn;
  const unsigned short* kp = kbf + (size_t)bh * Ln * DHn;
  const unsigned short* vp = vtb + (size_t)bh * DHn * Ln;
  const int q0 = qt * 128 + w * 32;

  __shared__ __align__(16) unsigned short ldsK[2][4096];   // 2 x 8KB
  __shared__ __align__(16) unsigned short ldsV[2][4096];
  __shared__ __align__(16) unsigned short plds[4][32][72]; // per-wave P (32 q-rows)

  const unsigned short* gK[2];
  const unsigned short* gV[2];
  #pragma unroll
  for (int i = 0; i < 2; i++){
    int bc = w * 2 + i;             // 0..7
    int ks = bc >> 2, j = bc & 3;
    int row = j * 16 + lr, col = ks * 32 + lg * 8;
    gK[i] = kp + (size_t)row * DHn + col;   // + t*4096 per tile
    gV[i] = vp + (size_t)row * Ln  + col;   // + t*64 per tile
  }

  short8v aq[2][2];                  // [qfrag][ks]
  #pragma unroll
  for (int f = 0; f < 2; f++)
    #pragma unroll
    for (int ks = 0; ks < 2; ks++)
      aq[f][ks] = *reinterpret_cast<const short8v*>(
          qp + (size_t)(q0 + f * 16 + lr) * DHn + ks * 32 + lg * 8);

  floatx4 accO[2][4] = {};
  float lsacc[2][4] = {{0.f,0.f,0.f,0.f},{0.f,0.f,0.f,0.f}};

  const int* mrow = kmask + b * Ln;
  int mkA[4], mkB[4];

  #pragma unroll
  for (int i = 0; i < 2; i++){
    gload16(gK[i], &ldsK[0][(w * 2 + i) * 512]);
    gload16(gV[i], &ldsV[0][(w * 2 + i) * 512]);
  }
  #pragma unroll
  for (int j = 0; j < 4; j++) mkA[j] = mrow[j * 16 + lr];

  for (int t = 0; t < 16; t++){
    const int cur = t & 1;
    asm volatile("s_waitcnt vmcnt(0)" ::: "memory");
    __syncthreads();
    if (t < 15){
      #pragma unroll
      for (int i = 0; i < 2; i++){
        gload16(gK[i] + (size_t)(t + 1) * 4096, &ldsK[cur ^ 1][(w * 2 + i) * 512]);
        gload16(gV[i] + (size_t)(t + 1) * 64,   &ldsV[cur ^ 1][(w * 2 + i) * 512]);
      }
      #pragma unroll
      for (int j = 0; j < 4; j++) mkB[j] = mrow[(t + 1) * 64 + j * 16 + lr];
    }

    floatx4 s[2][4] = {};
    #pragma unroll
    for (int ks = 0; ks < 2; ks++)
      #pragma unroll
      for (int j = 0; j < 4; j++){
        short8v bk = *reinterpret_cast<const short8v*>(&ldsK[cur][((ks * 4 + j) * 64 + lane) * 8]);
        s[0][j] = __builtin_amdgcn_mfma_f32_16x16x32_bf16(aq[0][ks], bk, s[0][j], 0, 0, 0);
        s[1][j] = __builtin_amdgcn_mfma_f32_16x16x32_bf16(aq[1][ks], bk, s[1][j], 0, 0, 0);
      }
    if (__all(mkA[0] > 0 && mkA[1] > 0 && mkA[2] > 0 && mkA[3] > 0)){
      #pragma unroll
      for (int f = 0; f < 2; f++)
        #pragma unroll
        for (int j = 0; j < 4; j++)
          #pragma unroll
          for (int r = 0; r < 4; r++){
            float p = __builtin_amdgcn_exp2f(s[f][j][r]);
            lsacc[f][r] += p;
            plds[w][f * 16 + lg * 4 + r][j * 16 + lr] = f2b_fast(p);
          }
    } else {
      #pragma unroll
      for (int j = 0; j < 4; j++){
        const float madd = mkA[j] > 0 ? 0.f : -1e9f;
        #pragma unroll
        for (int f = 0; f < 2; f++)
          #pragma unroll
          for (int r = 0; r < 4; r++){
            float p = __builtin_amdgcn_exp2f(s[f][j][r] + madd);
            lsacc[f][r] += p;
            plds[w][f * 16 + lg * 4 + r][j * 16 + lr] = f2b_fast(p);
          }
      }
    }
    #pragma unroll
    for (int ks = 0; ks < 2; ks++){
      short8v pa0 = *reinterpret_cast<const short8v*>(&plds[w][lr][ks * 32 + lg * 8]);
      short8v pa1 = *reinterpret_cast<const short8v*>(&plds[w][16 + lr][ks * 32 + lg * 8]);
      #pragma unroll
      for (int n = 0; n < 4; n++){
        short8v bv = *reinterpret_cast<const short8v*>(&ldsV[cur][((ks * 4 + n) * 64 + lane) * 8]);
        accO[0][n] = __builtin_amdgcn_mfma_f32_16x16x32_bf16(pa0, bv, accO[0][n], 0, 0, 0);
        accO[1][n] = __builtin_amdgcn_mfma_f32_16x16x32_bf16(pa1, bv, accO[1][n], 0, 0, 0);
      }
    }
    #pragma unroll
    for (int j = 0; j < 4; j++) mkA[j] = mkB[j];
  }

  #pragma unroll
  for (int f = 0; f < 2; f++)
    #pragma unroll
    for (int r = 0; r < 4; r++){
      lsacc[f][r] += __shfl_xor(lsacc[f][r], 1, 64);
      lsacc[f][r] += __shfl_xor(lsacc[f][r], 2, 64);
      lsacc[f][r] += __shfl_xor(lsacc[f][r], 4, 64);
      lsacc[f][r] += __shfl_xor(lsacc[f][r], 8, 64);
      lsacc[f][r] = 1.f / fmaxf(lsacc[f][r], 1e-20f);
    }
  #pragma unroll
  for (int f = 0; f < 2; f++)
    #pragma unroll
    for (int n = 0; n < 4; n++)
      #pragma unroll
      for (int r = 0; r < 4; r++){
        float o = accO[f][n][r] * lsacc[f][r];
        int q = q0 + f * 16 + lg * 4 + r;
        ctx[((size_t)(b * Ln + q)) * Dn + h * DHn + n * 16 + lr] = f2b_fast(o);
      }
}

// ---------------------------------------------------------------------------
// LayerNorm: one block per row of x[4096][1024] fp32 -> out fp32
// ---------------------------------------------------------------------------
__global__ __launch_bounds__(256) void ln_k(const float* __restrict__ x,
    const float* __restrict__ g, const float* __restrict__ bt, float* __restrict__ out)
{
  const int row = blockIdx.x;
  const int tid = threadIdx.x;
  float4 v = *reinterpret_cast<const float4*>(x + (size_t)row * 1024 + tid * 4);
  float s  = v.x + v.y + v.z + v.w;
  float sq = v.x * v.x + v.y * v.y + v.z * v.z + v.w * v.w;
  #pragma unroll
  for (int off = 32; off >= 1; off >>= 1){
    s  += __shfl_xor(s, off, 64);
    sq += __shfl_xor(sq, off, 64);
  }
  __shared__ float psm[4], pqm[4];
  const int w = tid >> 6;
  if ((tid & 63) == 0){ psm[w] = s; pqm[w] = sq; }
  __syncthreads();
  s  = psm[0] + psm[1] + psm[2] + psm[3];
  sq = pqm[0] + pqm[1] + pqm[2] + pqm[3];
  const float mean = s * (1.f / 1024.f);
  const float var  = sq * (1.f / 1024.f) - mean * mean;
  const float inv  = rsqrtf(var + 1e-5f);
  float4 gg = *reinterpret_cast<const float4*>(g  + tid * 4);
  float4 bb = *reinterpret_cast<const float4*>(bt + tid * 4);
  float4 o;
  o.x = (v.x - mean) * inv * gg.x + bb.x;
  o.y = (v.y - mean) * inv * gg.y + bb.y;
  o.z = (v.z - mean) * inv * gg.z + bb.z;
  o.w = (v.w - mean) * inv * gg.w + bb.w;
  *reinterpret_cast<float4*>(out + (size_t)row * 1024 + tid * 4) = o;
}

// ---------------------------------------------------------------------------
extern "C" void kernel_launch(void* const* d_in, const int* in_sizes, int n_in,
                              void* d_out, int out_size, void* d_ws, size_t ws_size,
                              hipStream_t stream)
{
  const float* Qin = (const float*)d_in[0];
  const float* Kin = (const float*)d_in[1];
  const float* Vin = (const float*)d_in[2];
  const int*   Kms = (const int*)d_in[3];
  const float* WQ  = (const float*)d_in[4];
  const float* bQ  = (const float*)d_in[5];
  const float* WK  = (const float*)d_in[6];
  const float* bK  = (const float*)d_in[7];
  const float* WV  = (const float*)d_in[8];
  const float* bV  = (const float*)d_in[9];
  const float* WO  = (const float*)d_in[10];
  const float* bO  = (const float*)d_in[11];
  const float* lng = (const float*)d_in[12];
  const float* lnb = (const float*)d_in[13];

  char* ws = (char*)d_ws;
  const size_t MB = 1024u * 1024u;
  unsigned short* wqt = (unsigned short*)(ws + 0 * MB);    // 1024x1024 bf16 = 2MB
  unsigned short* wkt = (unsigned short*)(ws + 2 * MB);
  unsigned short* wvt = (unsigned short*)(ws + 4 * MB);
  unsigned short* wot = (unsigned short*)(ws + 6 * MB);
  unsigned short* qbf = (unsigned short*)(ws + 8 * MB);    // [B,H,L,DH] bf16 = 8MB
  unsigned short* kbf = (unsigned short*)(ws + 16 * MB);
  unsigned short* vtb = (unsigned short*)(ws + 24 * MB);   // [B,H,DH,L]
  unsigned short* ctx = (unsigned short*)(ws + 32 * MB);   // [B,L,D] bf16
  float*          xbf = (float*)(ws + 40 * MB);            // [M,D] fp32 = 16MB
  // bf16 copies of Q,K,V inputs -- alias regions that are dead until later:
  unsigned short* cv0 = (unsigned short*)(ws + 32 * MB);   // aliases ctx (written later by attn)
  unsigned short* cv1 = (unsigned short*)(ws + 40 * MB);   // aliases xbf[0:8MB] (written later by gemmo)
  unsigned short* cv2 = (unsigned short*)(ws + 48 * MB);   // aliases xbf[8:16MB]

  dim3 blk(256);
  wconv4_k<<<dim3(16, 16, 4), blk, 0, stream>>>(WQ, WK, WV, WO, wqt, wkt, wvt, wot);
  tobf16x3_k<<<12288, blk, 0, stream>>>(Qin, Kin, Vin, cv0, cv1, cv2);

  const float QSCL = 0.125f * 1.44269504088896f;  // fold 1/sqrt(dh) * log2(e) into q
  gemmqkv_k<<<768, blk, 0, stream>>>(cv0, cv1, cv2, wqt, wkt, wvt,
                                     bQ, bK, bV, qbf, kbf, vtb, QSCL);

  attn_k<<<dim3(64, 8), blk, 0, stream>>>(qbf, kbf, vtb, Kms, ctx);

  gemmo_k<<<256, blk, 0, stream>>>(ctx, wot, bO, xbf, Qin);

  ln_k<<<4096, blk, 0, stream>>>(xbf, lng, lnb, (float*)d_out);
}

// Round 13
// 120.331 us; speedup vs baseline: 1.5202x; 1.1423x over previous
//
#include <hip/hip_runtime.h>
#include <hip/hip_bf16.h>
#include <stdint.h>

// Problem constants
#define Bn 4
#define Ln 1024
#define Dn 1024
#define Hn 16
#define DHn 64
#define Mn (Bn*Ln)   // 4096 tokens

typedef __attribute__((ext_vector_type(8))) short short8v;   // 8 x bf16 (4 VGPRs)
typedef __attribute__((ext_vector_type(4))) float floatx4;   // MFMA accumulator

__device__ __forceinline__ unsigned short f2b(float f){
  union { float f; unsigned u; } v; v.f = f;
  unsigned r = (v.u + 0x7FFFu + ((v.u >> 16) & 1u)) >> 16;  // RNE
  return (unsigned short)r;
}
__device__ __forceinline__ unsigned short f2b_fast(float f){
  __hip_bfloat16 h = __float2bfloat16(f);   // compiler-native cvt (RNE)
  return *reinterpret_cast<unsigned short*>(&h);
}

// global -> LDS direct copy, 16B per lane.
typedef const unsigned __attribute__((address_space(1)))* gas1_t;
typedef unsigned __attribute__((address_space(3)))* las3_t;
__device__ __forceinline__ void gload16(const void* g, void* l){
  __builtin_amdgcn_global_load_lds((gas1_t)(uintptr_t)g, (las3_t)(uintptr_t)l, 16, 0, 0);
}

// ---------------------------------------------------------------------------
// fp32 -> bf16 streaming convert, all three inputs in one launch
// ---------------------------------------------------------------------------
__global__ __launch_bounds__(256) void tobf16x3_k(const float* __restrict__ x0,
    const float* __restrict__ x1, const float* __restrict__ x2,
    unsigned short* __restrict__ o0, unsigned short* __restrict__ o1,
    unsigned short* __restrict__ o2)
{
  const int i = blockIdx.x * 256 + threadIdx.x;      // [0, 3*2^20)
  const int sel = i >> 20, idx = i & 0xFFFFF;
  const float* x = sel == 0 ? x0 : (sel == 1 ? x1 : x2);
  unsigned short* o = sel == 0 ? o0 : (sel == 1 ? o1 : o2);
  float4 v = reinterpret_cast<const float4*>(x)[idx];
  union { unsigned short u[4]; uint2 q; } p;
  p.u[0] = f2b(v.x); p.u[1] = f2b(v.y); p.u[2] = f2b(v.z); p.u[3] = f2b(v.w);
  reinterpret_cast<uint2*>(o)[idx] = p.q;
}

// ---------------------------------------------------------------------------
// Weight transpose + fp32->bf16 convert, all 4 weights in one launch
// ---------------------------------------------------------------------------
__global__ __launch_bounds__(256) void wconv4_k(const float* __restrict__ W0,
    const float* __restrict__ W1, const float* __restrict__ W2,
    const float* __restrict__ W3, unsigned short* __restrict__ Wt0,
    unsigned short* __restrict__ Wt1, unsigned short* __restrict__ Wt2,
    unsigned short* __restrict__ Wt3)
{
  const float* W; unsigned short* Wt;
  switch (blockIdx.z){
    case 0: W = W0; Wt = Wt0; break;
    case 1: W = W1; Wt = Wt1; break;
    case 2: W = W2; Wt = Wt2; break;
    default: W = W3; Wt = Wt3; break;
  }
  __shared__ float tile[64][65];
  const int nb = blockIdx.x * 64, kb = blockIdx.y * 64;
  const int tx = threadIdx.x & 63, ty = threadIdx.x >> 6;  // ty 0..3
  #pragma unroll
  for (int r = 0; r < 64; r += 4)
    tile[r + ty][tx] = W[(size_t)(kb + r + ty) * 1024 + nb + tx];
  __syncthreads();
  #pragma unroll
  for (int r = 0; r < 64; r += 4)
    Wt[(size_t)(nb + r + ty) * 1024 + kb + tx] = f2b(tile[tx][r + ty]);
}

// ---------------------------------------------------------------------------
// 8-PHASE 256x256 GEMM (guide m201-style template, adapted to K=1024).
// 512 thr = 8 waves (2M x 4N); per-wave C = 128x64 = acc[8][4].
// Slice = (K-tile t, ks-half) = A(256x32) + B(256x32) = 32KB; 4 slots = 128KB.
// Per K-tile: 4 phases (mhalf x ks), each: {stage half-slice; 4-8 ds_read;
// setprio(1); 16 MFMA; setprio(0)}; ONE vmcnt(4) per K-tile at group start
// (never drains mid-loop; ~6 phases of load cover); raw s_barrier at p0
// (confirms tile t block-wide + WAR for slot (2t-1)) and p2 (WAR for slot
// (2t), overwritten by slice 2t+4). Lane-major LDS -> conflict-free reads.
//  MODE 0: out bf16 [B,H,L,DH] (scaled)   MODE 2: out bf16 [B,H,DH,L]
// ---------------------------------------------------------------------------
template<int MODE>
__device__ __forceinline__ void gemm8_core(const unsigned short* __restrict__ Ab,
    const unsigned short* __restrict__ Btp, const float* __restrict__ bias,
    void* __restrict__ outp, float scale, unsigned short* lds, int nt, int mt)
{
  const int tid = threadIdx.x;                 // 0..511
  const int lane = tid & 63, wave = tid >> 6;  // 8 waves
  const int wr = wave >> 2, wc = wave & 3;     // 2 x 4
  const int lg = lane >> 4, lr = lane & 15;
  const int m0 = mt * 256, n0 = nt * 256;

  // staging: chunk c = tid + 512*i, c in [0,1024); c -> row/col within slice
  const unsigned short* gAb[2];
  const unsigned short* gBb[2];
  int ldso[2];
  #pragma unroll
  for (int i = 0; i < 2; i++){
    int c = tid + 512 * i;
    int g16 = c >> 6, lrr = c & 15, lgg = (c >> 4) & 3;
    int row = g16 * 16 + lrr;
    gAb[i] = Ab  + (size_t)(m0 + row) * 1024 + lgg * 8;
    gBb[i] = Btp + (size_t)(n0 + row) * 1024 + lgg * 8;
    ldso[i] = c * 8;
  }
  auto stageA = [&](int sg){
    unsigned short* slot = lds + (sg & 3) * 16384;
    const int kcol = (sg >> 1) * 64 + (sg & 1) * 32;
    #pragma unroll
    for (int i = 0; i < 2; i++) gload16(gAb[i] + kcol, &slot[ldso[i]]);
  };
  auto stageB = [&](int sg){
    unsigned short* slot = lds + (sg & 3) * 16384 + 8192;
    const int kcol = (sg >> 1) * 64 + (sg & 1) * 32;
    #pragma unroll
    for (int i = 0; i < 2; i++) gload16(gBb[i] + kcol, &slot[ldso[i]]);
  };

  floatx4 acc[8][4] = {};

  // prologue: slices 0,1,2 (12 loads/thread in flight)
  stageA(0); stageB(0); stageA(1); stageB(1); stageA(2); stageB(2);

  for (int t = 0; t < 16; t++){
    unsigned short* slot0 = lds + ((2 * t) & 3) * 16384;       // slice 2t   (ks0)
    unsigned short* slot1 = lds + ((2 * t + 1) & 3) * 16384;   // slice 2t+1 (ks1)
    short8v af[4], bf[4];
    // ---- p0: confirm tile t; stage (t+1,ks1)-A; compute (m0,ks0) ----
    if (t < 15) asm volatile("s_waitcnt vmcnt(4)" ::: "memory");
    else        asm volatile("s_waitcnt vmcnt(0)" ::: "memory");
    __builtin_amdgcn_s_barrier();
    __builtin_amdgcn_sched_barrier(0);
    if (t < 15) stageA(2 * t + 3);
    #pragma unroll
    for (int n = 0; n < 4; n++)
      bf[n] = *reinterpret_cast<const short8v*>(&slot0[8192 + ((wc * 4 + n) * 64 + lane) * 8]);
    #pragma unroll
    for (int i2 = 0; i2 < 4; i2++)
      af[i2] = *reinterpret_cast<const short8v*>(&slot0[((wr * 8 + i2) * 64 + lane) * 8]);
    __builtin_amdgcn_s_setprio(1);
    #pragma unroll
    for (int a = 0; a < 4; a++)
      #pragma unroll
      for (int n = 0; n < 4; n++)
        acc[a][n] = __builtin_amdgcn_mfma_f32_16x16x32_bf16(af[a], bf[n], acc[a][n], 0, 0, 0);
    __builtin_amdgcn_s_setprio(0);
    // ---- p1: stage (t+1,ks1)-B; compute (m1,ks0) ----
    if (t < 15) stageB(2 * t + 3);
    #pragma unroll
    for (int i2 = 0; i2 < 4; i2++)
      af[i2] = *reinterpret_cast<const short8v*>(&slot0[((wr * 8 + 4 + i2) * 64 + lane) * 8]);
    __builtin_amdgcn_s_setprio(1);
    #pragma unroll
    for (int a = 0; a < 4; a++)
      #pragma unroll
      for (int n = 0; n < 4; n++)
        acc[4 + a][n] = __builtin_amdgcn_mfma_f32_16x16x32_bf16(af[a], bf[n], acc[4 + a][n], 0, 0, 0);
    __builtin_amdgcn_s_setprio(0);
    // ---- p2: barrier (slot(2t) reads done block-wide); stage (t+2,ks0)-A;
    //          compute (m0,ks1) ----
    __builtin_amdgcn_sched_barrier(0);
    __builtin_amdgcn_s_barrier();
    __builtin_amdgcn_sched_barrier(0);
    if (t < 14) stageA(2 * t + 4);
    #pragma unroll
    for (int n = 0; n < 4; n++)
      bf[n] = *reinterpret_cast<const short8v*>(&slot1[8192 + ((wc * 4 + n) * 64 + lane) * 8]);
    #pragma unroll
    for (int i2 = 0; i2 < 4; i2++)
      af[i2] = *reinterpret_cast<const short8v*>(&slot1[((wr * 8 + i2) * 64 + lane) * 8]);
    __builtin_amdgcn_s_setprio(1);
    #pragma unroll
    for (int a = 0; a < 4; a++)
      #pragma unroll
      for (int n = 0; n < 4; n++)
        acc[a][n] = __builtin_amdgcn_mfma_f32_16x16x32_bf16(af[a], bf[n], acc[a][n], 0, 0, 0);
    __builtin_amdgcn_s_setprio(0);
    // ---- p3: stage (t+2,ks0)-B; compute (m1,ks1) ----
    if (t < 14) stageB(2 * t + 4);
    #pragma unroll
    for (int i2 = 0; i2 < 4; i2++)
      af[i2] = *reinterpret_cast<const short8v*>(&slot1[((wr * 8 + 4 + i2) * 64 + lane) * 8]);
    __builtin_amdgcn_s_setprio(1);
    #pragma unroll
    for (int a = 0; a < 4; a++)
      #pragma unroll
      for (int n = 0; n < 4; n++)
        acc[4 + a][n] = __builtin_amdgcn_mfma_f32_16x16x32_bf16(af[a], bf[n], acc[4 + a][n], 0, 0, 0);
    __builtin_amdgcn_s_setprio(0);
    __builtin_amdgcn_sched_barrier(0);
  }

  if constexpr (MODE == 2){
    // transpose epilogue: C^T (256x256 bf16 = exactly 128KB) via XOR swizzle
    __syncthreads();
    #pragma unroll
    for (int n = 0; n < 4; n++){
      const int gn_l = wc * 64 + n * 16 + lr;
      const float bb = bias[n0 + gn_l];
      const int X = (gn_l & 7) << 3;
      #pragma unroll
      for (int a = 0; a < 8; a++){
        const int gm_l = wr * 128 + a * 16 + lg * 4;
        union { unsigned short u[4]; uint2 q; } pk;
        #pragma unroll
        for (int r = 0; r < 4; r++) pk.u[r] = f2b((acc[a][n][r] + bb) * scale);
        *reinterpret_cast<uint2*>(&lds[gn_l * 256 + (gm_l ^ X)]) = pk.q;
      }
    }
    __syncthreads();
    const int bb2 = m0 >> 10, l0 = m0 & 1023;
    const int row = tid >> 1, colb = (tid & 1) * 128;
    const int h2 = (n0 + row) >> 6, d = (n0 + row) & 63;
    unsigned short* obase = (unsigned short*)outp +
        (((size_t)(bb2 * Hn + h2)) * DHn + d) * Ln + l0 + colb;
    const int XR = (row & 7) << 3;
    #pragma unroll
    for (int g = 0; g < 16; g++){
      short8v v = *reinterpret_cast<const short8v*>(&lds[row * 256 + ((colb + g * 8) ^ XR)]);
      *reinterpret_cast<short8v*>(obase + g * 8) = v;
    }
  } else {
    unsigned short* o = (unsigned short*)outp;
    #pragma unroll
    for (int n = 0; n < 4; n++){
      const int gn = n0 + wc * 64 + n * 16 + lr;
      const float bbv = bias[gn];
      const int h2 = gn >> 6, d = gn & 63;
      #pragma unroll
      for (int a = 0; a < 8; a++){
        const int gm0v = m0 + wr * 128 + a * 16 + lg * 4;
        #pragma unroll
        for (int r = 0; r < 4; r++){
          const int gm = gm0v + r;
          const int bb2 = gm >> 10, l = gm & 1023;
          o[(((size_t)(bb2 * Hn + h2)) * Ln + l) * DHn + d] = f2b((acc[a][n][r] + bbv) * scale);
        }
      }
    }
  }
}

// Fused Q/K/V projections, 8-phase: 192 blocks x 512 thr, 1 round.
// panel = z*16+mt (48); 4 nt-blocks of a panel share bid&7 -> same XCD.
__global__ __launch_bounds__(512, 2) void gemmqkv8_k(
    const unsigned short* __restrict__ A0, const unsigned short* __restrict__ A1,
    const unsigned short* __restrict__ A2, const unsigned short* __restrict__ W0,
    const unsigned short* __restrict__ W1, const unsigned short* __restrict__ W2,
    const float* __restrict__ b0, const float* __restrict__ b1,
    const float* __restrict__ b2, unsigned short* __restrict__ o0,
    unsigned short* __restrict__ o1, unsigned short* __restrict__ o2, float qscl)
{
  __shared__ __align__(16) unsigned short lds[65536];   // 128KB: 4 slice-slots
  const int g = blockIdx.x >> 3;               // 0..23
  const int nt = g & 3;
  const int panel = (g >> 2) * 8 + (blockIdx.x & 7);   // 0..47
  const int z = panel >> 4, mt = panel & 15;
  if (z == 0)
    gemm8_core<0>(A0, W0, b0, o0, qscl, lds, nt, mt);
  else if (z == 1)
    gemm8_core<0>(A1, W1, b1, o1, 1.f, lds, nt, mt);
  else
    gemm8_core<2>(A2, W2, b2, o2, 1.f, lds, nt, mt);
}

// ---------------------------------------------------------------------------
// O-projection GEMM (r12 depth-2 core, unchanged this round)
// ---------------------------------------------------------------------------
__device__ __forceinline__ void gemm_core3(const unsigned short* __restrict__ Ab,
    const unsigned short* __restrict__ Btp, const float* __restrict__ bias,
    float* __restrict__ outp, const float* __restrict__ resid,
    unsigned short* lds, int nt, int mt)
{
  const int tid = threadIdx.x;
  const int lane = tid & 63, wave = tid >> 6;
  const int wr = wave >> 1, wc = wave & 1;
  const int lg = lane >> 4, lr = lane & 15;
  const int m0 = mt * 128, n0 = nt * 128;

  const unsigned short* gA[4];
  const unsigned short* gB[4];
  #pragma unroll
  for (int i = 0; i < 4; i++){
    int c = (wave * 4 + i) * 64 + lane;
    int ks = c >> 9, r16 = (c >> 6) & 7, lhi = (c >> 4) & 3, lrr = c & 15;
    int row = r16 * 16 + lrr, col = ks * 32 + lhi * 8;
    gA[i] = Ab  + (size_t)(m0 + row) * 1024 + col;
    gB[i] = Btp + (size_t)(n0 + row) * 1024 + col;
  }

  floatx4 acc[4][4] = {};

  auto issue = [&](int t){
    unsigned short* bufA = lds + (t % 3) * 16384;
    unsigned short* bufB = bufA + 8192;
    #pragma unroll
    for (int i = 0; i < 4; i++){
      gload16(gA[i] + t * 64, &bufA[(wave * 4 + i) * 512]);
      gload16(gB[i] + t * 64, &bufB[(wave * 4 + i) * 512]);
    }
  };

  issue(0); issue(1);

  for (int kb = 0; kb < 16; kb++){
    unsigned short* bufA = lds + (kb % 3) * 16384;
    unsigned short* bufB = bufA + 8192;
    if (kb < 14){
      issue(kb + 2);
      asm volatile("s_waitcnt vmcnt(16)" ::: "memory");
    } else if (kb == 14){
      asm volatile("s_waitcnt vmcnt(8)" ::: "memory");
    } else {
      asm volatile("s_waitcnt vmcnt(0)" ::: "memory");
    }
    __builtin_amdgcn_s_barrier();
    __builtin_amdgcn_sched_barrier(0);
    #pragma unroll
    for (int ks = 0; ks < 2; ks++){
      short8v af[4], bfr[4];
      #pragma unroll
      for (int m = 0; m < 4; m++)
        af[m] = *reinterpret_cast<const short8v*>(&bufA[((ks * 8 + wr * 4 + m) * 64 + lane) * 8]);
      #pragma unroll
      for (int n = 0; n < 4; n++)
        bfr[n] = *reinterpret_cast<const short8v*>(&bufB[((ks * 8 + wc * 4 + n) * 64 + lane) * 8]);
      #pragma unroll
      for (int m = 0; m < 4; m++)
        #pragma unroll
        for (int n = 0; n < 4; n++)
          acc[m][n] = __builtin_amdgcn_mfma_f32_16x16x32_bf16(af[m], bfr[n], acc[m][n], 0, 0, 0);
    }
    __builtin_amdgcn_sched_barrier(0);
    __builtin_amdgcn_s_barrier();
  }

  #pragma unroll
  for (int n = 0; n < 4; n++){
    const int gn = n0 + wc * 64 + n * 16 + lr;
    const float bb = bias[gn];
    #pragma unroll
    for (int m = 0; m < 4; m++){
      const int gm0 = m0 + wr * 64 + m * 16 + lg * 4;
      #pragma unroll
      for (int r = 0; r < 4; r++){
        const int gm = gm0 + r;
        float v = acc[m][n][r] + bb;
        outp[(size_t)gm * Dn + gn] = v + resid[(size_t)gm * Dn + gn];
      }
    }
  }
}

__global__ __launch_bounds__(256) void gemmo_k(const unsigned short* __restrict__ Ab,
    const unsigned short* __restrict__ W, const float* __restrict__ bias,
    float* __restrict__ out, const float* __restrict__ resid)
{
  __shared__ __align__(16) unsigned short lds[49152];
  const int bid = blockIdx.x;
  const int xcd = bid & 7, k = bid >> 3;       // k: 0..31
  const int mt = xcd * 4 + (k >> 3);
  const int nt = k & 7;
  gemm_core3(Ab, W, bias, out, resid, lds, nt, mt);
}

// ---------------------------------------------------------------------------
// Flash attention v6 (unchanged): grid (B*H, L/128), 4 waves x 32 q-rows,
// KVBLK=64, no-max exp2 softmax, deferred denominator, dbuf K/V via
// global_load_lds, mask prefetch.
// ---------------------------------------------------------------------------
__global__ __launch_bounds__(256) void attn_k(const unsigned short* __restrict__ qb,
    const unsigned short* __restrict__ kbf, const unsigned short* __restrict__ vtb,
    const int* __restrict__ kmask, unsigned short* __restrict__ ctx)
{
  const int bh = blockIdx.x;        // 0..63
  const int qt = blockIdx.y;        // 0..7
  const int b = bh >> 4, h = bh & 15;
  const int tid = threadIdx.x;
  const int w = tid >> 6, lane = tid & 63;
  const int lg = lane >> 4, lr = lane & 15;

  const unsigned short* qp = qb  + (size_t)bh * Ln * DHn;
  const unsigned short* kp = kbf + (size_t)bh * Ln * DHn;
  const unsigned short* vp = vtb + (size_t)bh * DHn * Ln;
  const int q0 = qt * 128 + w * 32;

  __shared__ __align__(16) unsigned short ldsK[2][4096];   // 2 x 8KB
  __shared__ __align__(16) unsigned short ldsV[2][4096];
  __shared__ __align__(16) unsigned short plds[4][32][72]; // per-wave P (32 q-rows)

  const unsigned short* gK[2];
  const unsigned short* gV[2];
  #pragma unroll
  for (int i = 0; i < 2; i++){
    int bc = w * 2 + i;             // 0..7
    int ks = bc >> 2, j = bc & 3;
    int row = j * 16 + lr, col = ks * 32 + lg * 8;
    gK[i] = kp + (size_t)row * DHn + col;   // + t*4096 per tile
    gV[i] = vp + (size_t)row * Ln  + col;   // + t*64 per tile
  }

  short8v aq[2][2];                  // [qfrag][ks]
  #pragma unroll
  for (int f = 0; f < 2; f++)
    #pragma unroll
    for (int ks = 0; ks < 2; ks++)
      aq[f][ks] = *reinterpret_cast<const short8v*>(
          qp + (size_t)(q0 + f * 16 + lr) * DHn + ks * 32 + lg * 8);

  floatx4 accO[2][4] = {};
  float lsacc[2][4] = {{0.f,0.f,0.f,0.f},{0.f,0.f,0.f,0.f}};

  const int* mrow = kmask + b * Ln;
  int mkA[4], mkB[4];

  #pragma unroll
  for (int i = 0; i < 2; i++){
    gload16(gK[i], &ldsK[0][(w * 2 + i) * 512]);
    gload16(gV[i], &ldsV[0][(w * 2 + i) * 512]);
  }
  #pragma unroll
  for (int j = 0; j < 4; j++) mkA[j] = mrow[j * 16 + lr];

  for (int t = 0; t < 16; t++){
    const int cur = t & 1;
    asm volatile("s_waitcnt vmcnt(0)" ::: "memory");
    __syncthreads();
    if (t < 15){
      #pragma unroll
      for (int i = 0; i < 2; i++){
        gload16(gK[i] + (size_t)(t + 1) * 4096, &ldsK[cur ^ 1][(w * 2 + i) * 512]);
        gload16(gV[i] + (size_t)(t + 1) * 64,   &ldsV[cur ^ 1][(w * 2 + i) * 512]);
      }
      #pragma unroll
      for (int j = 0; j < 4; j++) mkB[j] = mrow[(t + 1) * 64 + j * 16 + lr];
    }

    floatx4 s[2][4] = {};
    #pragma unroll
    for (int ks = 0; ks < 2; ks++)
      #pragma unroll
      for (int j = 0; j < 4; j++){
        short8v bk = *reinterpret_cast<const short8v*>(&ldsK[cur][((ks * 4 + j) * 64 + lane) * 8]);
        s[0][j] = __builtin_amdgcn_mfma_f32_16x16x32_bf16(aq[0][ks], bk, s[0][j], 0, 0, 0);
        s[1][j] = __builtin_amdgcn_mfma_f32_16x16x32_bf16(aq[1][ks], bk, s[1][j], 0, 0, 0);
      }
    if (__all(mkA[0] > 0 && mkA[1] > 0 && mkA[2] > 0 && mkA[3] > 0)){
      #pragma unroll
      for (int f = 0; f < 2; f++)
        #pragma unroll
        for (int j = 0; j < 4; j++)
          #pragma unroll
          for (int r = 0; r < 4; r++){
            float p = __builtin_amdgcn_exp2f(s[f][j][r]);
            lsacc[f][r] += p;
            plds[w][f * 16 + lg * 4 + r][j * 16 + lr] = f2b_fast(p);
          }
    } else {
      #pragma unroll
      for (int j = 0; j < 4; j++){
        const float madd = mkA[j] > 0 ? 0.f : -1e9f;
        #pragma unroll
        for (int f = 0; f < 2; f++)
          #pragma unroll
          for (int r = 0; r < 4; r++){
            float p = __builtin_amdgcn_exp2f(s[f][j][r] + madd);
            lsacc[f][r] += p;
            plds[w][f * 16 + lg * 4 + r][j * 16 + lr] = f2b_fast(p);
          }
      }
    }
    #pragma unroll
    for (int ks = 0; ks < 2; ks++){
      short8v pa0 = *reinterpret_cast<const short8v*>(&plds[w][lr][ks * 32 + lg * 8]);
      short8v pa1 = *reinterpret_cast<const short8v*>(&plds[w][16 + lr][ks * 32 + lg * 8]);
      #pragma unroll
      for (int n = 0; n < 4; n++){
        short8v bv = *reinterpret_cast<const short8v*>(&ldsV[cur][((ks * 4 + n) * 64 + lane) * 8]);
        accO[0][n] = __builtin_amdgcn_mfma_f32_16x16x32_bf16(pa0, bv, accO[0][n], 0, 0, 0);
        accO[1][n] = __builtin_amdgcn_mfma_f32_16x16x32_bf16(pa1, bv, accO[1][n], 0, 0, 0);
      }
    }
    #pragma unroll
    for (int j = 0; j < 4; j++) mkA[j] = mkB[j];
  }

  #pragma unroll
  for (int f = 0; f < 2; f++)
    #pragma unroll
    for (int r = 0; r < 4; r++){
      lsacc[f][r] += __shfl_xor(lsacc[f][r], 1, 64);
      lsacc[f][r] += __shfl_xor(lsacc[f][r], 2, 64);
      lsacc[f][r] += __shfl_xor(lsacc[f][r], 4, 64);
      lsacc[f][r] += __shfl_xor(lsacc[f][r], 8, 64);
      lsacc[f][r] = 1.f / fmaxf(lsacc[f][r], 1e-20f);
    }
  #pragma unroll
  for (int f = 0; f < 2; f++)
    #pragma unroll
    for (int n = 0; n < 4; n++)
      #pragma unroll
      for (int r = 0; r < 4; r++){
        float o = accO[f][n][r] * lsacc[f][r];
        int q = q0 + f * 16 + lg * 4 + r;
        ctx[((size_t)(b * Ln + q)) * Dn + h * DHn + n * 16 + lr] = f2b_fast(o);
      }
}

// ---------------------------------------------------------------------------
// LayerNorm: one block per row of x[4096][1024] fp32 -> out fp32
// ---------------------------------------------------------------------------
__global__ __launch_bounds__(256) void ln_k(const float* __restrict__ x,
    const float* __restrict__ g, const float* __restrict__ bt, float* __restrict__ out)
{
  const int row = blockIdx.x;
  const int tid = threadIdx.x;
  float4 v = *reinterpret_cast<const float4*>(x + (size_t)row * 1024 + tid * 4);
  float s  = v.x + v.y + v.z + v.w;
  float sq = v.x * v.x + v.y * v.y + v.z * v.z + v.w * v.w;
  #pragma unroll
  for (int off = 32; off >= 1; off >>= 1){
    s  += __shfl_xor(s, off, 64);
    sq += __shfl_xor(sq, off, 64);
  }
  __shared__ float psm[4], pqm[4];
  const int w = tid >> 6;
  if ((tid & 63) == 0){ psm[w] = s; pqm[w] = sq; }
  __syncthreads();
  s  = psm[0] + psm[1] + psm[2] + psm[3];
  sq = pqm[0] + pqm[1] + pqm[2] + pqm[3];
  const float mean = s * (1.f / 1024.f);
  const float var  = sq * (1.f / 1024.f) - mean * mean;
  const float inv  = rsqrtf(var + 1e-5f);
  float4 gg = *reinterpret_cast<const float4*>(g  + tid * 4);
  float4 bb = *reinterpret_cast<const float4*>(bt + tid * 4);
  float4 o;
  o.x = (v.x - mean) * inv * gg.x + bb.x;
  o.y = (v.y - mean) * inv * gg.y + bb.y;
  o.z = (v.z - mean) * inv * gg.z + bb.z;
  o.w = (v.w - mean) * inv * gg.w + bb.w;
  *reinterpret_cast<float4*>(out + (size_t)row * 1024 + tid * 4) = o;
}

// ---------------------------------------------------------------------------
extern "C" void kernel_launch(void* const* d_in, const int* in_sizes, int n_in,
                              void* d_out, int out_size, void* d_ws, size_t ws_size,
                              hipStream_t stream)
{
  const float* Qin = (const float*)d_in[0];
  const float* Kin = (const float*)d_in[1];
  const float* Vin = (const float*)d_in[2];
  const int*   Kms = (const int*)d_in[3];
  const float* WQ  = (const float*)d_in[4];
  const float* bQ  = (const float*)d_in[5];
  const float* WK  = (const float*)d_in[6];
  const float* bK  = (const float*)d_in[7];
  const float* WV  = (const float*)d_in[8];
  const float* bV  = (const float*)d_in[9];
  const float* WO  = (const float*)d_in[10];
  const float* bO  = (const float*)d_in[11];
  const float* lng = (const float*)d_in[12];
  const float* lnb = (const float*)d_in[13];

  char* ws = (char*)d_ws;
  const size_t MB = 1024u * 1024u;
  unsigned short* wqt = (unsigned short*)(ws + 0 * MB);    // 1024x1024 bf16 = 2MB
  unsigned short* wkt = (unsigned short*)(ws + 2 * MB);
  unsigned short* wvt = (unsigned short*)(ws + 4 * MB);
  unsigned short* wot = (unsigned short*)(ws + 6 * MB);
  unsigned short* qbf = (unsigned short*)(ws + 8 * MB);    // [B,H,L,DH] bf16 = 8MB
  unsigned short* kbf = (unsigned short*)(ws + 16 * MB);
  unsigned short* vtb = (unsigned short*)(ws + 24 * MB);   // [B,H,DH,L]
  unsigned short* ctx = (unsigned short*)(ws + 32 * MB);   // [B,L,D] bf16
  float*          xbf = (float*)(ws + 40 * MB);            // [M,D] fp32 = 16MB
  // bf16 copies of Q,K,V inputs -- alias regions that are dead until later:
  unsigned short* cv0 = (unsigned short*)(ws + 32 * MB);   // aliases ctx (written later by attn)
  unsigned short* cv1 = (unsigned short*)(ws + 40 * MB);   // aliases xbf[0:8MB] (written later by gemmo)
  unsigned short* cv2 = (unsigned short*)(ws + 48 * MB);   // aliases xbf[8:16MB]

  dim3 blk(256);
  wconv4_k<<<dim3(16, 16, 4), blk, 0, stream>>>(WQ, WK, WV, WO, wqt, wkt, wvt, wot);
  tobf16x3_k<<<12288, blk, 0, stream>>>(Qin, Kin, Vin, cv0, cv1, cv2);

  const float QSCL = 0.125f * 1.44269504088896f;  // fold 1/sqrt(dh) * log2(e) into q
  gemmqkv8_k<<<192, dim3(512), 0, stream>>>(cv0, cv1, cv2, wqt, wkt, wvt,
                                            bQ, bK, bV, qbf, kbf, vtb, QSCL);

  attn_k<<<dim3(64, 8), blk, 0, stream>>>(qbf, kbf, vtb, Kms, ctx);

  gemmo_k<<<256, blk, 0, stream>>>(ctx, wot, bO, xbf, Qin);

  ln_k<<<4096, blk, 0, stream>>>(xbf, lng, lnb, (float*)d_out);
}